// Round 1
// baseline (611.187 us; speedup 1.0000x reference)
//
#include <hip/hip_runtime.h>
#include <stdint.h>

typedef unsigned short u16;
typedef __attribute__((ext_vector_type(8))) short s8v;
typedef __attribute__((ext_vector_type(4))) float f4v;

#define MFMA(a, b, c) __builtin_amdgcn_mfma_f32_16x16x32_bf16((a), (b), (c), 0, 0, 0)

__device__ __forceinline__ u16 f2b(float f) {
  uint32_t x = __float_as_uint(f);
  x += 0x7fff + ((x >> 16) & 1);   // RNE
  return (u16)(x >> 16);
}
__device__ __forceinline__ float b2f(u16 u) {
  return __uint_as_float(((uint32_t)u) << 16);
}

// async global->LDS, 16B per lane. LDS dest must be wave-uniform base + lane*16.
__device__ __forceinline__ void gll16(const void* g, void* l) {
  __builtin_amdgcn_global_load_lds((const __attribute__((address_space(1))) uint32_t*)g,
                                   (__attribute__((address_space(3))) uint32_t*)l, 16, 0, 0);
}

// ---------------- fp32 -> bf16 convert ----------------
__global__ void cvt_kernel(const float* __restrict__ src, u16* __restrict__ dst, int n8) {
  int i = blockIdx.x * 256 + threadIdx.x;
  if (i >= n8) return;
  const float4* s = (const float4*)src;
  float4 f0 = s[2 * (size_t)i], f1 = s[2 * (size_t)i + 1];
  s8v o;
  o[0] = (short)f2b(f0.x); o[1] = (short)f2b(f0.y); o[2] = (short)f2b(f0.z); o[3] = (short)f2b(f0.w);
  o[4] = (short)f2b(f1.x); o[5] = (short)f2b(f1.y); o[6] = (short)f2b(f1.z); o[7] = (short)f2b(f1.w);
  *(s8v*)(dst + 8 * (size_t)i) = o;
}

// ---------------- GEMM: C[m][n] = sum_k A[m][k] * W[n][k] + bias[n] ----------------
// MODE 0: C1 fp32 [M][N].  MODE 1: C1 bf16 [M][N].
// MODE 3: fused K/V (N=2048): n<1024 -> C1 bf16 [M][1024] (K); n>=1024 -> C2 bf16 transposed [1024][M] (V^T).
template <int MODE>
__global__ __launch_bounds__(256) void gemm_bt(const u16* __restrict__ A, const u16* __restrict__ W,
                                               const float* __restrict__ bias, const float* __restrict__ bias2,
                                               void* __restrict__ C1, void* __restrict__ C2,
                                               int M, int N, int K) {
  __shared__ u16 As[128 * 32];
  __shared__ u16 Bs[128 * 32];
  const int tid = threadIdx.x;
  const int l = tid & 63, wv = tid >> 6;
  const int wr = wv >> 1, wc = wv & 1;
  const int lr = l & 15, lg = l >> 4;
  const int m0 = blockIdx.y * 128, n0 = blockIdx.x * 128;
  const u16* Ag = A + (size_t)m0 * K;
  const u16* Wg = W + (size_t)n0 * K;

  f4v zero = {0.f, 0.f, 0.f, 0.f};
  f4v acc[4][4];
#pragma unroll
  for (int i = 0; i < 4; ++i)
#pragma unroll
    for (int j = 0; j < 4; ++j) acc[i][j] = zero;

  const int srow = tid >> 2;
  const int scol = (tid & 3) * 8;

  for (int kt = 0; kt < K; kt += 32) {
    __syncthreads();
    gll16(Ag + (size_t)srow * K + kt + scol,        &As[tid * 8]);
    gll16(Ag + (size_t)(srow + 64) * K + kt + scol, &As[2048 + tid * 8]);
    gll16(Wg + (size_t)srow * K + kt + scol,        &Bs[tid * 8]);
    gll16(Wg + (size_t)(srow + 64) * K + kt + scol, &Bs[2048 + tid * 8]);
    __syncthreads();   // compiler emits vmcnt(0) drain before barrier

    s8v af[4], bf[4];
#pragma unroll
    for (int i = 0; i < 4; ++i) af[i] = *(const s8v*)&As[(wr * 64 + i * 16 + lr) * 32 + lg * 8];
#pragma unroll
    for (int j = 0; j < 4; ++j) bf[j] = *(const s8v*)&Bs[(wc * 64 + j * 16 + lr) * 32 + lg * 8];
#pragma unroll
    for (int i = 0; i < 4; ++i)
#pragma unroll
      for (int j = 0; j < 4; ++j) acc[i][j] = MFMA(af[i], bf[j], acc[i][j]);
  }

#pragma unroll
  for (int i = 0; i < 4; ++i) {
#pragma unroll
    for (int j = 0; j < 4; ++j) {
#pragma unroll
      for (int r = 0; r < 4; ++r) {
        int rr = m0 + wr * 64 + i * 16 + lg * 4 + r;
        int cl = n0 + wc * 64 + j * 16 + lr;
        float v = acc[i][j][r];
        if (MODE == 0) {
          ((float*)C1)[(size_t)rr * N + cl] = v + bias[cl];
        } else if (MODE == 1) {
          ((u16*)C1)[(size_t)rr * N + cl] = f2b(v + bias[cl]);
        } else {
          if (cl < 1024) ((u16*)C1)[(size_t)rr * 1024 + cl] = f2b(v + bias[cl]);
          else           ((u16*)C2)[(size_t)(cl - 1024) * M + rr] = f2b(v + bias2[cl - 1024]);
        }
      }
    }
  }
}

// ---------------- RoPE (in place on bf16 q,k) ----------------
__global__ void rope_kernel(u16* __restrict__ q, u16* __restrict__ k, const int* __restrict__ pos) {
  int i = blockIdx.x * 256 + threadIdx.x;
  const int NQ = 2048 * 32 * 64;
  const int NK = 2048 * 8 * 64;
  u16* buf;
  int m, d, stride, h;
  if (i < NQ) { buf = q; m = i >> 11; h = (i >> 6) & 31; d = i & 63; stride = 4096; }
  else {
    i -= NQ; if (i >= NK) return;
    buf = k; m = i >> 9; h = (i >> 6) & 7; d = i & 63; stride = 1024;
  }
  size_t base = (size_t)m * stride + h * 128 + d;
  float a = b2f(buf[base]), b = b2f(buf[base + 64]);
  float p = (float)pos[m];
  // inv_freq = 10000^(-d/64) = 2^(-d * log2(1e4)/64)
  float ang = p * exp2f(-0.20762050593045952f * (float)d);
  float s, c;
  sincosf(ang, &s, &c);
  buf[base]      = f2b(a * c - b * s);
  buf[base + 64] = f2b(b * c + a * s);
}

// ---------------- flash attention ----------------
// grid: 32 q-heads x 32 q-tiles(64 rows). block: 4 waves, each wave owns 16 q rows.
__global__ __launch_bounds__(256) void attn_kernel(const u16* __restrict__ Q, const u16* __restrict__ Kb,
                                                   const u16* __restrict__ Vt, u16* __restrict__ Ao) {
  __shared__ u16 Ks[32][136];    // 32 kv rows x 128 d (+8 pad kills bank conflicts)
  __shared__ u16 Vs[128][40];    // V^T tile: 128 d x 32 kv (+8 pad)
  __shared__ u16 Ps[4][16 * 40]; // per-wave P buffer 16 q x 32 kv (+8 pad)
  const int tid = threadIdx.x;
  const int l = tid & 63, wv = tid >> 6;
  const int lr = l & 15, lg = l >> 4;
  const int qh = blockIdx.x >> 5, qt = blockIdx.x & 31;
  const int kh = qh >> 2;
  const int qrow = qt * 64 + wv * 16 + lr;

  s8v qf[4];
#pragma unroll
  for (int s = 0; s < 4; ++s)
    qf[s] = *(const s8v*)&Q[(size_t)qrow * 4096 + qh * 128 + s * 32 + lg * 8];

  f4v zero = {0.f, 0.f, 0.f, 0.f};
  f4v ao[8];
#pragma unroll
  for (int tt = 0; tt < 8; ++tt) ao[tt] = zero;
  float mrun[4], lrun[4];
#pragma unroll
  for (int r = 0; r < 4; ++r) { mrun[r] = -1e30f; lrun[r] = 0.f; }

  const u16* Kg = Kb + kh * 128;
  const u16* Vg = Vt + (size_t)(kh * 128) * 2048;
  const int skr = tid >> 4, skc = (tid & 15) * 8;
  const int svd = tid >> 2, svc = (tid & 3) * 8;

  for (int t = 0; t < 2048; t += 32) {
    __syncthreads();
    *(s8v*)&Ks[skr][skc]      = *(const s8v*)&Kg[(size_t)(t + skr) * 1024 + skc];
    *(s8v*)&Ks[16 + skr][skc] = *(const s8v*)&Kg[(size_t)(t + 16 + skr) * 1024 + skc];
    *(s8v*)&Vs[svd][svc]      = *(const s8v*)&Vg[(size_t)svd * 2048 + t + svc];
    *(s8v*)&Vs[64 + svd][svc] = *(const s8v*)&Vg[(size_t)(64 + svd) * 2048 + t + svc];
    __syncthreads();

    // S = Q K^T for this wave's 16 rows x 32 kv cols
    f4v c0 = zero, c1 = zero;
#pragma unroll
    for (int s = 0; s < 4; ++s) {
      s8v k0 = *(const s8v*)&Ks[lr][s * 32 + lg * 8];
      s8v k1 = *(const s8v*)&Ks[16 + lr][s * 32 + lg * 8];
      c0 = MFMA(qf[s], k0, c0);
      c1 = MFMA(qf[s], k1, c1);
    }

    // online softmax; rows of this lane: 4*lg + r; cols: lr (c0), 16+lr (c1)
    u16* Pw = Ps[wv];
#pragma unroll
    for (int r = 0; r < 4; ++r) {
      const float sc = 0.08838834764831845f;  // 1/sqrt(128)
      float s0 = c0[r] * sc, s1 = c1[r] * sc;
      float mx = fmaxf(s0, s1);
      mx = fmaxf(mx, __shfl_xor(mx, 1));
      mx = fmaxf(mx, __shfl_xor(mx, 2));
      mx = fmaxf(mx, __shfl_xor(mx, 4));
      mx = fmaxf(mx, __shfl_xor(mx, 8));
      float mnew = fmaxf(mrun[r], mx);
      float alpha = __expf(mrun[r] - mnew);
      mrun[r] = mnew;
      float p0 = __expf(s0 - mnew), p1 = __expf(s1 - mnew);
      float rs = p0 + p1;
      rs += __shfl_xor(rs, 1);
      rs += __shfl_xor(rs, 2);
      rs += __shfl_xor(rs, 4);
      rs += __shfl_xor(rs, 8);
      lrun[r] = lrun[r] * alpha + rs;
#pragma unroll
      for (int tt = 0; tt < 8; ++tt) ao[tt][r] *= alpha;
      Pw[(lg * 4 + r) * 40 + lr]      = f2b(p0);
      Pw[(lg * 4 + r) * 40 + 16 + lr] = f2b(p1);
    }

    // PV: A-frag of P from per-wave LDS (same wave wrote it; in-order + waitcnt)
    s8v pf = *(const s8v*)&Pw[lr * 40 + lg * 8];
#pragma unroll
    for (int tt = 0; tt < 8; ++tt) {
      s8v vf = *(const s8v*)&Vs[tt * 16 + lr][lg * 8];
      ao[tt] = MFMA(pf, vf, ao[tt]);
    }
  }

  float inv[4];
#pragma unroll
  for (int r = 0; r < 4; ++r) inv[r] = 1.f / lrun[r];
#pragma unroll
  for (int tt = 0; tt < 8; ++tt)
#pragma unroll
    for (int r = 0; r < 4; ++r)
      Ao[(size_t)(qt * 64 + wv * 16 + lg * 4 + r) * 4096 + qh * 128 + tt * 16 + lr] =
          f2b(ao[tt][r] * inv[r]);
}

extern "C" void kernel_launch(void* const* d_in, const int* in_sizes, int n_in,
                              void* d_out, int out_size, void* d_ws, size_t ws_size,
                              hipStream_t stream) {
  const float* x  = (const float*)d_in[0];
  const int*   pos = (const int*)d_in[1];
  const float* wq = (const float*)d_in[2];
  const float* bq = (const float*)d_in[3];
  const float* wk = (const float*)d_in[4];
  const float* bk = (const float*)d_in[5];
  const float* wv = (const float*)d_in[6];
  const float* bv = (const float*)d_in[7];
  const float* wo = (const float*)d_in[8];
  const float* bo = (const float*)d_in[9];
  float* out = (float*)d_out;

  char* ws = (char*)d_ws;
  u16* xb   = (u16*)(ws + 0);           // 16 MB  x bf16 [2048][4096]
  u16* wqb  = (u16*)(ws + 16777216);    // 32 MB  wq bf16 [4096][4096]
  u16* wkvb = (u16*)(ws + 50331648);    // 16 MB  wk|wv bf16 [2048][4096]
  u16* wob  = (u16*)(ws + 67108864);    // 32 MB  wo bf16 [4096][4096]
  u16* qb   = (u16*)(ws + 100663296);   // 16 MB  q bf16 [2048][4096]
  u16* kb   = (u16*)(ws + 117440512);   //  4 MB  k bf16 [2048][1024]
  u16* vT   = (u16*)(ws + 121634816);   //  4 MB  v^T bf16 [1024][2048]
  u16* ab   = (u16*)(ws + 125829120);   // 16 MB  attn out bf16 [2048][4096]
  // total 142,606,336 B of d_ws

  auto cv = [&](const float* s, u16* d, size_t n) {
    int n8 = (int)(n / 8);
    cvt_kernel<<<(n8 + 255) / 256, 256, 0, stream>>>(s, d, n8);
  };
  cv(x,  xb,   (size_t)2048 * 4096);
  cv(wq, wqb,  (size_t)4096 * 4096);
  cv(wk, wkvb, (size_t)1024 * 4096);
  cv(wv, wkvb + (size_t)1024 * 4096, (size_t)1024 * 4096);
  cv(wo, wob,  (size_t)4096 * 4096);

  gemm_bt<1><<<dim3(32, 16), 256, 0, stream>>>(xb, wqb, bq, nullptr, qb, nullptr, 2048, 4096, 4096);
  gemm_bt<3><<<dim3(16, 16), 256, 0, stream>>>(xb, wkvb, bk, bv, kb, vT, 2048, 2048, 4096);
  rope_kernel<<<(2048 * 32 * 64 + 2048 * 8 * 64) / 256, 256, 0, stream>>>(qb, kb, pos);
  attn_kernel<<<1024, 256, 0, stream>>>(qb, kb, vT, ab);
  gemm_bt<0><<<dim3(32, 16), 256, 0, stream>>>(ab, wob, bo, nullptr, (void*)out, nullptr, 2048, 4096, 4096);
}

// Round 2
// 457.774 us; speedup vs baseline: 1.3351x; 1.3351x over previous
//
#include <hip/hip_runtime.h>
#include <stdint.h>

typedef unsigned short u16;
typedef unsigned long long u64;
typedef __attribute__((ext_vector_type(8))) short s8v;
typedef __attribute__((ext_vector_type(4))) float f4v;

#define MFMA(a, b, c) __builtin_amdgcn_mfma_f32_16x16x32_bf16((a), (b), (c), 0, 0, 0)

__device__ __forceinline__ u16 f2b(float f) {
  uint32_t x = __float_as_uint(f);
  x += 0x7fff + ((x >> 16) & 1);   // RNE
  return (u16)(x >> 16);
}
__device__ __forceinline__ float b2f(u16 u) {
  return __uint_as_float(((uint32_t)u) << 16);
}

// async global->LDS, 16B per lane. LDS dest must be wave-uniform base + lane*16.
__device__ __forceinline__ void gll16(const void* g, void* l) {
  __builtin_amdgcn_global_load_lds((const __attribute__((address_space(1))) uint32_t*)g,
                                   (__attribute__((address_space(3))) uint32_t*)l, 16, 0, 0);
}

// ---------------- fp32 -> bf16 convert ----------------
__global__ void cvt_kernel(const float* __restrict__ src, u16* __restrict__ dst, int n8) {
  int i = blockIdx.x * 256 + threadIdx.x;
  if (i >= n8) return;
  const float4* s = (const float4*)src;
  float4 f0 = s[2 * (size_t)i], f1 = s[2 * (size_t)i + 1];
  s8v o;
  o[0] = (short)f2b(f0.x); o[1] = (short)f2b(f0.y); o[2] = (short)f2b(f0.z); o[3] = (short)f2b(f0.w);
  o[4] = (short)f2b(f1.x); o[5] = (short)f2b(f1.y); o[6] = (short)f2b(f1.z); o[7] = (short)f2b(f1.w);
  *(s8v*)(dst + 8 * (size_t)i) = o;
}

// ---------------- GEMM: C[m][n] = sum_k A[m][k] * W[n][k] + bias[n] ----------------
template <int MODE>
__global__ __launch_bounds__(256) void gemm_bt(const u16* __restrict__ A, const u16* __restrict__ W,
                                               const float* __restrict__ bias, const float* __restrict__ bias2,
                                               void* __restrict__ C1, void* __restrict__ C2,
                                               int M, int N, int K) {
  __shared__ u16 As[128 * 32];
  __shared__ u16 Bs[128 * 32];
  const int tid = threadIdx.x;
  const int l = tid & 63, wv = tid >> 6;
  const int wr = wv >> 1, wc = wv & 1;
  const int lr = l & 15, lg = l >> 4;
  const int m0 = blockIdx.y * 128, n0 = blockIdx.x * 128;
  const u16* Ag = A + (size_t)m0 * K;
  const u16* Wg = W + (size_t)n0 * K;

  f4v zero = {0.f, 0.f, 0.f, 0.f};
  f4v acc[4][4];
#pragma unroll
  for (int i = 0; i < 4; ++i)
#pragma unroll
    for (int j = 0; j < 4; ++j) acc[i][j] = zero;

  const int srow = tid >> 2;
  const int scol = (tid & 3) * 8;

  for (int kt = 0; kt < K; kt += 32) {
    __syncthreads();
    gll16(Ag + (size_t)srow * K + kt + scol,        &As[tid * 8]);
    gll16(Ag + (size_t)(srow + 64) * K + kt + scol, &As[2048 + tid * 8]);
    gll16(Wg + (size_t)srow * K + kt + scol,        &Bs[tid * 8]);
    gll16(Wg + (size_t)(srow + 64) * K + kt + scol, &Bs[2048 + tid * 8]);
    __syncthreads();

    s8v af[4], bf[4];
#pragma unroll
    for (int i = 0; i < 4; ++i) af[i] = *(const s8v*)&As[(wr * 64 + i * 16 + lr) * 32 + lg * 8];
#pragma unroll
    for (int j = 0; j < 4; ++j) bf[j] = *(const s8v*)&Bs[(wc * 64 + j * 16 + lr) * 32 + lg * 8];
#pragma unroll
    for (int i = 0; i < 4; ++i)
#pragma unroll
      for (int j = 0; j < 4; ++j) acc[i][j] = MFMA(af[i], bf[j], acc[i][j]);
  }

#pragma unroll
  for (int i = 0; i < 4; ++i) {
#pragma unroll
    for (int j = 0; j < 4; ++j) {
#pragma unroll
      for (int r = 0; r < 4; ++r) {
        int rr = m0 + wr * 64 + i * 16 + lg * 4 + r;
        int cl = n0 + wc * 64 + j * 16 + lr;
        float v = acc[i][j][r];
        if (MODE == 0) {
          ((float*)C1)[(size_t)rr * N + cl] = v + bias[cl];
        } else if (MODE == 1) {
          ((u16*)C1)[(size_t)rr * N + cl] = f2b(v + bias[cl]);
        } else {
          if (cl < 1024) ((u16*)C1)[(size_t)rr * 1024 + cl] = f2b(v + bias[cl]);
          else           ((u16*)C2)[(size_t)(cl - 1024) * M + rr] = f2b(v + bias2[cl - 1024]);
        }
      }
    }
  }
}

// ---------------- RoPE (in place on bf16 q,k) ----------------
__global__ void rope_kernel(u16* __restrict__ q, u16* __restrict__ k, const int* __restrict__ pos) {
  int i = blockIdx.x * 256 + threadIdx.x;
  const int NQ = 2048 * 32 * 64;
  const int NK = 2048 * 8 * 64;
  u16* buf;
  int m, d, stride, h;
  if (i < NQ) { buf = q; m = i >> 11; h = (i >> 6) & 31; d = i & 63; stride = 4096; }
  else {
    i -= NQ; if (i >= NK) return;
    buf = k; m = i >> 9; h = (i >> 6) & 7; d = i & 63; stride = 1024;
  }
  size_t base = (size_t)m * stride + h * 128 + d;
  float a = b2f(buf[base]), b = b2f(buf[base + 64]);
  float p = (float)pos[m];
  float ang = p * exp2f(-0.20762050593045952f * (float)d);
  float s, c;
  sincosf(ang, &s, &c);
  buf[base]      = f2b(a * c - b * s);
  buf[base + 64] = f2b(b * c + a * s);
}

// ---------------- flash attention ----------------
// grid: 32 heads x 16 q-tiles(128 rows). block: 8 waves, each wave owns 16 q rows.
// KVBLK=64. Swapped QK^T: lane (lr,lg) holds S[kv=16j+4lg+r][q=lr] -> softmax row is lane-local.
// K/V staged via global_load_lds with pre-swizzled global source; reads XOR byte^(16*(row&7)).
__global__ __launch_bounds__(512, 4) void attn_kernel(const u16* __restrict__ Q, const u16* __restrict__ Kb,
                                                      const u16* __restrict__ Vt, u16* __restrict__ Ao) {
  __shared__ __align__(16) u16 Ks[64 * 128];   // swizzled storage
  __shared__ __align__(16) u16 Vs[128 * 64];   // V^T tile, swizzled storage
  __shared__ __align__(16) u16 Ps[8 * 16 * 64]; // per-wave P, swizzled
  const int tid = threadIdx.x;
  const int l = tid & 63, wv = tid >> 6;
  const int lr = l & 15, lg = l >> 4;
  const int head = blockIdx.x >> 4, qt = blockIdx.x & 15;
  const int kh = head >> 2;
  const int qrow = qt * 128 + wv * 16 + lr;

  s8v qf[4];
#pragma unroll
  for (int s = 0; s < 4; ++s)
    qf[s] = *(const s8v*)&Q[(size_t)qrow * 4096 + head * 128 + s * 32 + lg * 8];

  f4v zero = {0.f, 0.f, 0.f, 0.f};
  f4v ao[8];
#pragma unroll
  for (int tt = 0; tt < 8; ++tt) ao[tt] = zero;
  float mrun = -1e30f, lrun = 0.f;

  // staging chunk assignments (2 K-chunks + 2 V-chunks per thread)
  const int ki0 = tid, ki1 = tid + 512;
  const int kr0 = ki0 >> 4, kc0 = (ki0 & 15) ^ (kr0 & 7);
  const int kr1 = ki1 >> 4, kc1 = (ki1 & 15) ^ (kr1 & 7);
  const int vr0 = ki0 >> 3, vc0 = (ki0 & 7) ^ (vr0 & 7);
  const int vr1 = ki1 >> 3, vc1 = (ki1 & 7) ^ (vr1 & 7);
  const u16* Kg = Kb + kh * 128;
  const u16* Vg = Vt + (size_t)(kh * 128) * 2048;
  const u16* kp0 = Kg + (size_t)kr0 * 1024 + kc0 * 8;
  const u16* kp1 = Kg + (size_t)kr1 * 1024 + kc1 * 8;
  const u16* vp0 = Vg + (size_t)vr0 * 2048 + vc0 * 8;
  const u16* vp1 = Vg + (size_t)vr1 * 2048 + vc1 * 8;

  char* KsB = (char*)Ks;
  char* VsB = (char*)Vs;
  char* PwB = (char*)Ps + wv * 2048;    // this wave's 16x64 P tile (2 KB)
  const int swz = 16 * (lr & 7);
  const float C2 = 0.12753102f;         // (1/sqrt(128)) * log2(e)

  for (int t = 0; t < 2048; t += 64) {
    __syncthreads();
    gll16(kp0 + (size_t)t * 1024, KsB + ki0 * 16);
    gll16(kp1 + (size_t)t * 1024, KsB + ki1 * 16);
    gll16(vp0 + t,                VsB + ki0 * 16);
    gll16(vp1 + t,                VsB + ki1 * 16);
    __syncthreads();

    // QK^T swapped: c[j] = K[16j..16j+15] x Q^T -> S[kv][q=lr]
    f4v c[4];
#pragma unroll
    for (int j = 0; j < 4; ++j) c[j] = zero;
#pragma unroll
    for (int s = 0; s < 4; ++s) {
#pragma unroll
      for (int j = 0; j < 4; ++j) {
        s8v kf = *(const s8v*)(KsB + (16 * j + lr) * 256 + (((4 * s + lg) * 16) ^ swz));
        c[j] = MFMA(kf, qf[s], c[j]);
      }
    }

    // row (q=lr) softmax stats, lane-local over 16 values + 2 shuffles
    float mx = fmaxf(fmaxf(c[0][0], c[0][1]), fmaxf(c[0][2], c[0][3]));
#pragma unroll
    for (int j = 1; j < 4; ++j)
      mx = fmaxf(mx, fmaxf(fmaxf(c[j][0], c[j][1]), fmaxf(c[j][2], c[j][3])));
    mx = fmaxf(mx, __shfl_xor(mx, 16));
    mx = fmaxf(mx, __shfl_xor(mx, 32));
    float m2x = mx * C2;

    if (!__all(m2x - mrun <= 8.f)) {      // defer-max: rescale only on real growth
      float mnew = fmaxf(mrun, m2x);
      float alpha = __builtin_amdgcn_exp2f(mrun - mnew);
      float ar[4];
#pragma unroll
      for (int r = 0; r < 4; ++r) ar[r] = __shfl(alpha, 4 * lg + r);
#pragma unroll
      for (int tt = 0; tt < 8; ++tt)
#pragma unroll
        for (int r = 0; r < 4; ++r) ao[tt][r] *= ar[r];
      lrun *= alpha;
      mrun = mnew;
    }

    // P = 2^(S*C2 - mrun), pack 4 bf16 -> 8B LDS store (swizzled), accumulate row sum
    float rs = 0.f;
#pragma unroll
    for (int j = 0; j < 4; ++j) {
      float p0 = __builtin_amdgcn_exp2f(__builtin_fmaf(c[j][0], C2, -mrun));
      float p1 = __builtin_amdgcn_exp2f(__builtin_fmaf(c[j][1], C2, -mrun));
      float p2 = __builtin_amdgcn_exp2f(__builtin_fmaf(c[j][2], C2, -mrun));
      float p3 = __builtin_amdgcn_exp2f(__builtin_fmaf(c[j][3], C2, -mrun));
      rs += (p0 + p1) + (p2 + p3);
      uint32_t lo = (uint32_t)f2b(p0) | ((uint32_t)f2b(p1) << 16);
      uint32_t hi = (uint32_t)f2b(p2) | ((uint32_t)f2b(p3) << 16);
      u64 pak = (u64)lo | ((u64)hi << 32);
      *(u64*)(PwB + lr * 128 + ((32 * j + 8 * lg) ^ swz)) = pak;
    }
    rs += __shfl_xor(rs, 16);
    rs += __shfl_xor(rs, 32);
    lrun += rs;

    // PV: O[q][d] += P x V  (A-frag P from own-wave LDS, B-frag V^T swizzled)
#pragma unroll
    for (int h = 0; h < 2; ++h) {
      s8v pf = *(const s8v*)(PwB + lr * 128 + ((64 * h + 16 * lg) ^ swz));
#pragma unroll
      for (int tt = 0; tt < 8; ++tt) {
        s8v vf = *(const s8v*)(VsB + (16 * tt + lr) * 128 + (((4 * h + lg) * 16) ^ swz));
        ao[tt] = MFMA(pf, vf, ao[tt]);
      }
    }
  }

  float inv = 1.f / lrun;
  float ir[4];
#pragma unroll
  for (int r = 0; r < 4; ++r) ir[r] = __shfl(inv, 4 * lg + r);
#pragma unroll
  for (int tt = 0; tt < 8; ++tt)
#pragma unroll
    for (int r = 0; r < 4; ++r)
      Ao[(size_t)(qt * 128 + wv * 16 + 4 * lg + r) * 4096 + head * 128 + 16 * tt + lr] =
          f2b(ao[tt][r] * ir[r]);
}

extern "C" void kernel_launch(void* const* d_in, const int* in_sizes, int n_in,
                              void* d_out, int out_size, void* d_ws, size_t ws_size,
                              hipStream_t stream) {
  const float* x  = (const float*)d_in[0];
  const int*   pos = (const int*)d_in[1];
  const float* wq = (const float*)d_in[2];
  const float* bq = (const float*)d_in[3];
  const float* wk = (const float*)d_in[4];
  const float* bk = (const float*)d_in[5];
  const float* wv = (const float*)d_in[6];
  const float* bv = (const float*)d_in[7];
  const float* wo = (const float*)d_in[8];
  const float* bo = (const float*)d_in[9];
  float* out = (float*)d_out;

  char* ws = (char*)d_ws;
  u16* xb   = (u16*)(ws + 0);           // 16 MB  x bf16 [2048][4096]
  u16* wqb  = (u16*)(ws + 16777216);    // 32 MB  wq bf16 [4096][4096]
  u16* wkvb = (u16*)(ws + 50331648);    // 16 MB  wk|wv bf16 [2048][4096]
  u16* wob  = (u16*)(ws + 67108864);    // 32 MB  wo bf16 [4096][4096]
  u16* qb   = (u16*)(ws + 100663296);   // 16 MB  q bf16 [2048][4096]
  u16* kb   = (u16*)(ws + 117440512);   //  4 MB  k bf16 [2048][1024]
  u16* vT   = (u16*)(ws + 121634816);   //  4 MB  v^T bf16 [1024][2048]
  u16* ab   = (u16*)(ws + 125829120);   // 16 MB  attn out bf16 [2048][4096]

  auto cv = [&](const float* s, u16* d, size_t n) {
    int n8 = (int)(n / 8);
    cvt_kernel<<<(n8 + 255) / 256, 256, 0, stream>>>(s, d, n8);
  };
  cv(x,  xb,   (size_t)2048 * 4096);
  cv(wq, wqb,  (size_t)4096 * 4096);
  cv(wk, wkvb, (size_t)1024 * 4096);
  cv(wv, wkvb + (size_t)1024 * 4096, (size_t)1024 * 4096);
  cv(wo, wob,  (size_t)4096 * 4096);

  gemm_bt<1><<<dim3(32, 16), 256, 0, stream>>>(xb, wqb, bq, nullptr, qb, nullptr, 2048, 4096, 4096);
  gemm_bt<3><<<dim3(16, 16), 256, 0, stream>>>(xb, wkvb, bk, bv, kb, vT, 2048, 2048, 4096);
  rope_kernel<<<(2048 * 32 * 64 + 2048 * 8 * 64) / 256, 256, 0, stream>>>(qb, kb, pos);
  attn_kernel<<<512, 512, 0, stream>>>(qb, kb, vT, ab);
  gemm_bt<0><<<dim3(32, 16), 256, 0, stream>>>(ab, wob, bo, nullptr, (void*)out, nullptr, 2048, 4096, 4096);
}

// Round 3
// 366.778 us; speedup vs baseline: 1.6664x; 1.2481x over previous
//
#include <hip/hip_runtime.h>
#include <stdint.h>

typedef unsigned short u16;
typedef unsigned long long u64;
typedef __attribute__((ext_vector_type(8))) short s8v;
typedef __attribute__((ext_vector_type(4))) float f4v;

#define MFMA(a, b, c) __builtin_amdgcn_mfma_f32_16x16x32_bf16((a), (b), (c), 0, 0, 0)

__device__ __forceinline__ u16 f2b(float f) {
  uint32_t x = __float_as_uint(f);
  x += 0x7fff + ((x >> 16) & 1);   // RNE
  return (u16)(x >> 16);
}
__device__ __forceinline__ float b2f(u16 u) {
  return __uint_as_float(((uint32_t)u) << 16);
}

// async global->LDS, 16B per lane. LDS dest must be wave-uniform base + lane*16.
__device__ __forceinline__ void gll16(const void* g, void* l) {
  __builtin_amdgcn_global_load_lds((const __attribute__((address_space(1))) uint32_t*)g,
                                   (__attribute__((address_space(3))) uint32_t*)l, 16, 0, 0);
}
__device__ __forceinline__ void bar() { __builtin_amdgcn_s_barrier(); }

// ---------------- fp32 -> bf16 convert ----------------
__global__ void cvt_kernel(const float* __restrict__ src, u16* __restrict__ dst, int n8) {
  int i = blockIdx.x * 256 + threadIdx.x;
  if (i >= n8) return;
  const float4* s = (const float4*)src;
  float4 f0 = s[2 * (size_t)i], f1 = s[2 * (size_t)i + 1];
  s8v o;
  o[0] = (short)f2b(f0.x); o[1] = (short)f2b(f0.y); o[2] = (short)f2b(f0.z); o[3] = (short)f2b(f0.w);
  o[4] = (short)f2b(f1.x); o[5] = (short)f2b(f1.y); o[6] = (short)f2b(f1.z); o[7] = (short)f2b(f1.w);
  *(s8v*)(dst + 8 * (size_t)i) = o;
}

// ---------------- 8-phase GEMM: C[m][n] = sum_k A[m][k]*W[n][k] + bias[n] ----------------
// BN=256, BK=64, 2 K-tiles/iter, 8 waves (2M x 4N), dbuf LDS, XOR-swizzled tiles,
// counted vmcnt(4) at phases 4/8 only. MODE 0: fp32 out. MODE 2: fused QKV split write.
template <int BM, int MODE>
__global__ __launch_bounds__(512, 2) void gemm8p(
    const u16* __restrict__ A, const u16* __restrict__ W,
    const float* __restrict__ bA, const float* __restrict__ bB, const float* __restrict__ bC,
    float* __restrict__ Cf, u16* __restrict__ Cq, u16* __restrict__ Ck, u16* __restrict__ Cv,
    int Ncols, int K) {
  extern __shared__ u16 smem[];
  // elem offsets: A-even [0, BM*64), A-odd, B-even [2*BM*64, +16384), B-odd
  constexpr int AO = BM * 64;
  constexpr int BE = 2 * BM * 64;
  constexpr int BO = BE + 16384;
  constexpr int MI = BM / 64;     // A frags per quadrant

  const int tid = threadIdx.x;
  const int l = tid & 63, wv = tid >> 6;
  const int wm = wv >> 2, wn = wv & 3;
  const int lr = l & 15, lg = l >> 4;
  const int swz = 16 * (lr & 7);
  const int wrow = wm * (BM / 2);

  // XCD-aware block swizzle (nwg % 8 == 0 for all our launches)
  const int nwg = gridDim.x;
  int bid = blockIdx.x;
  bid = (bid & 7) * (nwg >> 3) + (bid >> 3);
  const int NB = Ncols >> 8;
  const int m0 = (bid / NB) * BM, n0 = (bid % NB) * 256;

  const size_t K64 = (size_t)64 * K;

  // staging: per-thread source row/col (inverse-swizzled), linear LDS dest
  const int sr = tid >> 3;
  const int sc = ((tid & 7) ^ (sr & 7)) * 8;
  const u16* gA = A + (size_t)(m0 + sr) * K + sc;
  const u16* gB = W + (size_t)(n0 + sr) * K + sc;

  auto STA = [&](int P, int h, int kt) {
    const u16* g = gA + (size_t)(h * (BM / 2)) * K + (size_t)kt * 64;
    u16* d = smem + (P ? AO : 0) + h * (BM / 2) * 64 + tid * 8;
    gll16(g, d);
    if constexpr (BM == 256) gll16(g + K64, d + 4096);
  };
  auto STB = [&](int P, int h, int kt) {
    const u16* g = gB + (size_t)(h * 128) * K + (size_t)kt * 64;
    u16* d = smem + (P ? BO : BE) + h * 8192 + tid * 8;
    gll16(g, d);
    gll16(g + K64, d + 4096);
  };

  const char* smc = (const char*)smem;
  s8v a[MI][2], b0[2][2], b1[2][2];
  auto LDA = [&](int P, int QR) {
#pragma unroll
    for (int mi = 0; mi < MI; ++mi)
#pragma unroll
      for (int kk = 0; kk < 2; ++kk)
        a[mi][kk] = *(const s8v*)(smc + (P ? AO * 2 : 0) +
            (wrow + QR * (BM / 4) + mi * 16 + lr) * 128 + ((kk * 64 + lg * 16) ^ swz));
  };
  auto LDB = [&](int P, int QC, s8v bb[2][2]) {
#pragma unroll
    for (int ni = 0; ni < 2; ++ni)
#pragma unroll
      for (int kk = 0; kk < 2; ++kk)
        bb[ni][kk] = *(const s8v*)(smc + (P ? BO * 2 : BE * 2) +
            (wn * 64 + QC * 32 + ni * 16 + lr) * 128 + ((kk * 64 + lg * 16) ^ swz));
  };

  f4v acc[BM / 32][4];
#pragma unroll
  for (int i = 0; i < BM / 32; ++i)
#pragma unroll
    for (int j = 0; j < 4; ++j) acc[i][j] = {0.f, 0.f, 0.f, 0.f};

#define PHMF(QR, QC, B)                                                        \
  __builtin_amdgcn_s_setprio(1);                                               \
  _Pragma("unroll") for (int mi = 0; mi < MI; ++mi)                            \
    _Pragma("unroll") for (int ni = 0; ni < 2; ++ni)                           \
      _Pragma("unroll") for (int kk = 0; kk < 2; ++kk)                         \
        acc[(QR) * MI + mi][(QC) * 2 + ni] =                                   \
            MFMA(a[mi][kk], B[ni][kk], acc[(QR) * MI + mi][(QC) * 2 + ni]);    \
  __builtin_amdgcn_s_setprio(0);

  // prologue: stage Kt0 (even slot) fully + Kt1's B halves (odd slot)
  STB(0, 0, 0); STB(0, 1, 0);
  STA(0, 0, 0); STA(0, 1, 0);
  STB(1, 0, 1); STB(1, 1, 1);
  asm volatile("s_waitcnt vmcnt(4)" ::: "memory");
  bar();

  const int ITERS = K >> 7;
  for (int i = 0; i < ITERS; ++i) {
    const int kn = 2 * i + 2;
    const bool more = (i + 1 < ITERS);
    // phi1: even (qr0,qc0); stage A-lo-odd (Kt 2i+1)
    LDA(0, 0); LDB(0, 0, b0);
    STA(1, 0, 2 * i + 1);
    bar(); PHMF(0, 0, b0); bar();
    // phi2: even (qr0,qc1); stage A-hi-odd
    LDB(0, 1, b1);
    STA(1, 1, 2 * i + 1);
    bar(); PHMF(0, 1, b1); bar();
    // phi3: even (qr1,qc1); stage B-lo-even(next)
    LDA(0, 1);
    if (more) STB(0, 0, kn);
    bar(); PHMF(1, 1, b1); bar();
    // phi4: even (qr1,qc0); stage B-hi-even(next); counted wait
    if (more) STB(0, 1, kn);
    bar(); PHMF(1, 0, b0);
    asm volatile("s_waitcnt vmcnt(4)" ::: "memory");
    bar();
    // phi5: odd (qr0,qc0); stage A-lo-even(next)
    LDA(1, 0); LDB(1, 0, b0);
    if (more) STA(0, 0, kn);
    bar(); PHMF(0, 0, b0); bar();
    // phi6: odd (qr0,qc1); stage A-hi-even(next)
    LDB(1, 1, b1);
    if (more) STA(0, 1, kn);
    bar(); PHMF(0, 1, b1); bar();
    // phi7: odd (qr1,qc1); stage B-lo-odd(next)
    LDA(1, 1);
    if (more) STB(1, 0, 2 * i + 3);
    bar(); PHMF(1, 1, b1); bar();
    // phi8: odd (qr1,qc0); stage B-hi-odd(next); counted wait
    if (more) STB(1, 1, 2 * i + 3);
    bar(); PHMF(1, 0, b0);
    asm volatile("s_waitcnt vmcnt(4)" ::: "memory");
    bar();
  }
#undef PHMF

#pragma unroll
  for (int fi = 0; fi < BM / 32; ++fi)
#pragma unroll
    for (int fj = 0; fj < 4; ++fj)
#pragma unroll
      for (int r = 0; r < 4; ++r) {
        int rr = m0 + wrow + fi * 16 + lg * 4 + r;
        int cl = n0 + wn * 64 + fj * 16 + lr;
        float v = acc[fi][fj][r];
        if (MODE == 0) {
          Cf[(size_t)rr * 4096 + cl] = v + bA[cl];
        } else {
          if (cl < 4096)      Cq[(size_t)rr * 4096 + cl] = f2b(v + bA[cl]);
          else if (cl < 5120) Ck[(size_t)rr * 1024 + (cl - 4096)] = f2b(v + bB[cl - 4096]);
          else                Cv[(size_t)(cl - 5120) * 2048 + rr] = f2b(v + bC[cl - 5120]);
        }
      }
}

// ---------------- RoPE (in place on bf16 q,k) ----------------
__global__ void rope_kernel(u16* __restrict__ q, u16* __restrict__ k, const int* __restrict__ pos) {
  int i = blockIdx.x * 256 + threadIdx.x;
  const int NQ = 2048 * 32 * 64;
  const int NK = 2048 * 8 * 64;
  u16* buf;
  int m, d, stride, h;
  if (i < NQ) { buf = q; m = i >> 11; h = (i >> 6) & 31; d = i & 63; stride = 4096; }
  else {
    i -= NQ; if (i >= NK) return;
    buf = k; m = i >> 9; h = (i >> 6) & 7; d = i & 63; stride = 1024;
  }
  size_t base = (size_t)m * stride + h * 128 + d;
  float a = b2f(buf[base]), b = b2f(buf[base + 64]);
  float p = (float)pos[m];
  float ang = p * exp2f(-0.20762050593045952f * (float)d);
  float s, c;
  sincosf(ang, &s, &c);
  buf[base]      = f2b(a * c - b * s);
  buf[base + 64] = f2b(b * c + a * s);
}

// ---------------- flash attention ----------------
// grid: 32 heads x 16 q-tiles(128 rows). block: 8 waves, each wave owns 16 q rows.
__global__ __launch_bounds__(512, 4) void attn_kernel(const u16* __restrict__ Q, const u16* __restrict__ Kb,
                                                      const u16* __restrict__ Vt, u16* __restrict__ Ao) {
  __shared__ __align__(16) u16 Ks[64 * 128];
  __shared__ __align__(16) u16 Vs[128 * 64];
  __shared__ __align__(16) u16 Ps[8 * 16 * 64];
  const int tid = threadIdx.x;
  const int l = tid & 63, wv = tid >> 6;
  const int lr = l & 15, lg = l >> 4;
  const int head = blockIdx.x >> 4, qt = blockIdx.x & 15;
  const int kh = head >> 2;
  const int qrow = qt * 128 + wv * 16 + lr;

  s8v qf[4];
#pragma unroll
  for (int s = 0; s < 4; ++s)
    qf[s] = *(const s8v*)&Q[(size_t)qrow * 4096 + head * 128 + s * 32 + lg * 8];

  f4v zero = {0.f, 0.f, 0.f, 0.f};
  f4v ao[8];
#pragma unroll
  for (int tt = 0; tt < 8; ++tt) ao[tt] = zero;
  float mrun = -1e30f, lrun = 0.f;

  const int ki0 = tid, ki1 = tid + 512;
  const int kr0 = ki0 >> 4, kc0 = (ki0 & 15) ^ (kr0 & 7);
  const int kr1 = ki1 >> 4, kc1 = (ki1 & 15) ^ (kr1 & 7);
  const int vr0 = ki0 >> 3, vc0 = (ki0 & 7) ^ (vr0 & 7);
  const int vr1 = ki1 >> 3, vc1 = (ki1 & 7) ^ (vr1 & 7);
  const u16* Kg = Kb + kh * 128;
  const u16* Vg = Vt + (size_t)(kh * 128) * 2048;
  const u16* kp0 = Kg + (size_t)kr0 * 1024 + kc0 * 8;
  const u16* kp1 = Kg + (size_t)kr1 * 1024 + kc1 * 8;
  const u16* vp0 = Vg + (size_t)vr0 * 2048 + vc0 * 8;
  const u16* vp1 = Vg + (size_t)vr1 * 2048 + vc1 * 8;

  char* KsB = (char*)Ks;
  char* VsB = (char*)Vs;
  char* PwB = (char*)Ps + wv * 2048;
  const int swz = 16 * (lr & 7);
  const float C2 = 0.12753102f;         // (1/sqrt(128)) * log2(e)

  for (int t = 0; t < 2048; t += 64) {
    __syncthreads();
    gll16(kp0 + (size_t)t * 1024, KsB + ki0 * 16);
    gll16(kp1 + (size_t)t * 1024, KsB + ki1 * 16);
    gll16(vp0 + t,                VsB + ki0 * 16);
    gll16(vp1 + t,                VsB + ki1 * 16);
    __syncthreads();

    f4v c[4];
#pragma unroll
    for (int j = 0; j < 4; ++j) c[j] = zero;
#pragma unroll
    for (int s = 0; s < 4; ++s) {
#pragma unroll
      for (int j = 0; j < 4; ++j) {
        s8v kf = *(const s8v*)(KsB + (16 * j + lr) * 256 + (((4 * s + lg) * 16) ^ swz));
        c[j] = MFMA(kf, qf[s], c[j]);
      }
    }

    float mx = fmaxf(fmaxf(c[0][0], c[0][1]), fmaxf(c[0][2], c[0][3]));
#pragma unroll
    for (int j = 1; j < 4; ++j)
      mx = fmaxf(mx, fmaxf(fmaxf(c[j][0], c[j][1]), fmaxf(c[j][2], c[j][3])));
    mx = fmaxf(mx, __shfl_xor(mx, 16));
    mx = fmaxf(mx, __shfl_xor(mx, 32));
    float m2x = mx * C2;

    if (!__all(m2x - mrun <= 8.f)) {
      float mnew = fmaxf(mrun, m2x);
      float alpha = __builtin_amdgcn_exp2f(mrun - mnew);
      float ar[4];
#pragma unroll
      for (int r = 0; r < 4; ++r) ar[r] = __shfl(alpha, 4 * lg + r);
#pragma unroll
      for (int tt = 0; tt < 8; ++tt)
#pragma unroll
        for (int r = 0; r < 4; ++r) ao[tt][r] *= ar[r];
      lrun *= alpha;
      mrun = mnew;
    }

    float rs = 0.f;
#pragma unroll
    for (int j = 0; j < 4; ++j) {
      float p0 = __builtin_amdgcn_exp2f(__builtin_fmaf(c[j][0], C2, -mrun));
      float p1 = __builtin_amdgcn_exp2f(__builtin_fmaf(c[j][1], C2, -mrun));
      float p2 = __builtin_amdgcn_exp2f(__builtin_fmaf(c[j][2], C2, -mrun));
      float p3 = __builtin_amdgcn_exp2f(__builtin_fmaf(c[j][3], C2, -mrun));
      rs += (p0 + p1) + (p2 + p3);
      uint32_t lo = (uint32_t)f2b(p0) | ((uint32_t)f2b(p1) << 16);
      uint32_t hi = (uint32_t)f2b(p2) | ((uint32_t)f2b(p3) << 16);
      u64 pak = (u64)lo | ((u64)hi << 32);
      *(u64*)(PwB + lr * 128 + ((32 * j + 8 * lg) ^ swz)) = pak;
    }
    rs += __shfl_xor(rs, 16);
    rs += __shfl_xor(rs, 32);
    lrun += rs;

#pragma unroll
    for (int h = 0; h < 2; ++h) {
      s8v pf = *(const s8v*)(PwB + lr * 128 + ((64 * h + 16 * lg) ^ swz));
#pragma unroll
      for (int tt = 0; tt < 8; ++tt) {
        s8v vf = *(const s8v*)(VsB + (16 * tt + lr) * 128 + (((4 * h + lg) * 16) ^ swz));
        ao[tt] = MFMA(pf, vf, ao[tt]);
      }
    }
  }

  float inv = 1.f / lrun;
  float ir[4];
#pragma unroll
  for (int r = 0; r < 4; ++r) ir[r] = __shfl(inv, 4 * lg + r);
#pragma unroll
  for (int tt = 0; tt < 8; ++tt)
#pragma unroll
    for (int r = 0; r < 4; ++r)
      Ao[(size_t)(qt * 128 + wv * 16 + 4 * lg + r) * 4096 + head * 128 + 16 * tt + lr] =
          f2b(ao[tt][r] * ir[r]);
}

extern "C" void kernel_launch(void* const* d_in, const int* in_sizes, int n_in,
                              void* d_out, int out_size, void* d_ws, size_t ws_size,
                              hipStream_t stream) {
  const float* x  = (const float*)d_in[0];
  const int*   pos = (const int*)d_in[1];
  const float* wq = (const float*)d_in[2];
  const float* bq = (const float*)d_in[3];
  const float* wk = (const float*)d_in[4];
  const float* bk = (const float*)d_in[5];
  const float* wv = (const float*)d_in[6];
  const float* bv = (const float*)d_in[7];
  const float* wo = (const float*)d_in[8];
  const float* bo = (const float*)d_in[9];
  float* out = (float*)d_out;

  char* ws = (char*)d_ws;
  u16* xb   = (u16*)(ws + 0);           // 16 MB  x bf16 [2048][4096]
  u16* wqkv = (u16*)(ws + 16777216);    // 48 MB  wq|wk|wv bf16 [6144][4096]
  u16* wob  = (u16*)(ws + 67108864);    // 32 MB  wo bf16 [4096][4096]
  u16* qb   = (u16*)(ws + 100663296);   // 16 MB  q bf16 [2048][4096]
  u16* kb   = (u16*)(ws + 117440512);   //  4 MB  k bf16 [2048][1024]
  u16* vT   = (u16*)(ws + 121634816);   //  4 MB  v^T bf16 [1024][2048]
  u16* ab   = (u16*)(ws + 125829120);   // 16 MB  attn out bf16 [2048][4096]

  auto cv = [&](const float* s, u16* d, size_t n) {
    int n8 = (int)(n / 8);
    cvt_kernel<<<(n8 + 255) / 256, 256, 0, stream>>>(s, d, n8);
  };
  cv(x,  xb,   (size_t)2048 * 4096);
  cv(wq, wqkv, (size_t)4096 * 4096);
  cv(wk, wqkv + (size_t)4096 * 4096, (size_t)1024 * 4096);
  cv(wv, wqkv + (size_t)5120 * 4096, (size_t)1024 * 4096);
  cv(wo, wob,  (size_t)4096 * 4096);

  // fused QKV projection: [2048][4096] x [6144][4096]^T -> q, k, v^T
  gemm8p<256, 2><<<192, 512, 131072, stream>>>(xb, wqkv, bq, bk, bv,
                                               nullptr, qb, kb, vT, 6144, 4096);
  rope_kernel<<<(2048 * 32 * 64 + 2048 * 8 * 64) / 256, 256, 0, stream>>>(qb, kb, pos);
  attn_kernel<<<512, 512, 0, stream>>>(qb, kb, vT, ab);
  // output projection: fp32 out + bias
  gemm8p<128, 0><<<256, 512, 98304, stream>>>(ab, wob, bo, nullptr, nullptr,
                                              out, nullptr, nullptr, nullptr, 4096, 4096);
}

// Round 4
// 347.032 us; speedup vs baseline: 1.7612x; 1.0569x over previous
//
#include <hip/hip_runtime.h>
#include <stdint.h>

typedef unsigned short u16;
typedef unsigned long long u64;
typedef __attribute__((ext_vector_type(8))) short s8v;
typedef __attribute__((ext_vector_type(4))) float f4v;

#define MFMA(a, b, c) __builtin_amdgcn_mfma_f32_16x16x32_bf16((a), (b), (c), 0, 0, 0)

__device__ __forceinline__ u16 f2b(float f) {
  uint32_t x = __float_as_uint(f);
  x += 0x7fff + ((x >> 16) & 1);   // RNE
  return (u16)(x >> 16);
}
__device__ __forceinline__ float b2f(u16 u) {
  return __uint_as_float(((uint32_t)u) << 16);
}

// async global->LDS, 16B per lane. LDS dest must be wave-uniform base + lane*16.
__device__ __forceinline__ void gll16(const void* g, void* l) {
  __builtin_amdgcn_global_load_lds((const __attribute__((address_space(1))) uint32_t*)g,
                                   (__attribute__((address_space(3))) uint32_t*)l, 16, 0, 0);
}
__device__ __forceinline__ void bar() { __builtin_amdgcn_s_barrier(); }

// ---------------- fp32 -> bf16 convert ----------------
__global__ void cvt_kernel(const float* __restrict__ src, u16* __restrict__ dst, int n8) {
  int i = blockIdx.x * 256 + threadIdx.x;
  if (i >= n8) return;
  const float4* s = (const float4*)src;
  float4 f0 = s[2 * (size_t)i], f1 = s[2 * (size_t)i + 1];
  s8v o;
  o[0] = (short)f2b(f0.x); o[1] = (short)f2b(f0.y); o[2] = (short)f2b(f0.z); o[3] = (short)f2b(f0.w);
  o[4] = (short)f2b(f1.x); o[5] = (short)f2b(f1.y); o[6] = (short)f2b(f1.z); o[7] = (short)f2b(f1.w);
  *(s8v*)(dst + 8 * (size_t)i) = o;
}

// ---------------- 8-phase GEMM, weights-as-A orientation ----------------
// A = weights [F][K] (M-dim = features), B = activations [2048][K] (N-dim = tokens).
// C[feat][tok] = sum_k A[feat][k]*B[tok][k] + bias[feat].
// BN=256 tokens, BK=64, 8 waves (2M x 4N), dbuf LDS, XOR swizzle, vmcnt(4) at phases 4/8.
// MODE 2 (BM=256): QKV fused. m-tiles 0-15 -> q (token-major, LDS transpose),
//   16-19 -> k (token-major, LDS transpose), 20-23 -> vT (feature-major, direct).
// MODE 0 (BM=128): fp32 out[tok][4096] via LDS transpose.
template <int BM, int MODE>
__global__ __launch_bounds__(512, 2) void gemm8p(
    const u16* __restrict__ A, const u16* __restrict__ Bact,
    const float* __restrict__ bA, const float* __restrict__ bB, const float* __restrict__ bC,
    float* __restrict__ Cf, u16* __restrict__ Cq, u16* __restrict__ Ck, u16* __restrict__ Cv,
    int K) {
  extern __shared__ u16 smem[];
  constexpr int AO = BM * 64;          // A-odd elem offset
  constexpr int BE = 2 * BM * 64;      // B-even
  constexpr int BO = BE + 16384;       // B-odd
  constexpr int MI = BM / 64;          // A frags per quadrant

  const int tid = threadIdx.x;
  const int l = tid & 63, wv = tid >> 6;
  const int wm = wv >> 2, wn = wv & 3;
  const int lr = l & 15, lg = l >> 4;
  const int swz = 16 * (lr & 7);
  const int wrow = wm * (BM / 2);

  // XCD-aware swizzle, m-major logical order: each XCD owns contiguous feat-rows,
  // reusing its A tiles from L2 across all 8 token-tiles.
  const int nwg = gridDim.x;
  int bid = blockIdx.x;
  bid = (bid & 7) * (nwg >> 3) + (bid >> 3);
  const int NB = 8;                    // 2048 tokens / 256
  const int m0 = (bid / NB) * BM, n0 = (bid % NB) * 256;

  const size_t K64 = (size_t)64 * K;

  const int sr = tid >> 3;
  const int sc = ((tid & 7) ^ (sr & 7)) * 8;
  const u16* gA = A + (size_t)(m0 + sr) * K + sc;
  const u16* gB = Bact + (size_t)(n0 + sr) * K + sc;

  auto STA = [&](int P, int h, int kt) {
    const u16* g = gA + (size_t)(h * (BM / 2)) * K + (size_t)kt * 64;
    u16* d = smem + (P ? AO : 0) + h * (BM / 2) * 64 + tid * 8;
    gll16(g, d);
    if constexpr (BM == 256) gll16(g + K64, d + 4096);
  };
  auto STB = [&](int P, int h, int kt) {
    const u16* g = gB + (size_t)(h * 128) * K + (size_t)kt * 64;
    u16* d = smem + (P ? BO : BE) + h * 8192 + tid * 8;
    gll16(g, d);
    gll16(g + K64, d + 4096);
  };

  const char* smc = (const char*)smem;
  s8v a[MI][2], b0[2][2], b1[2][2];
  auto LDA = [&](int P, int QR) {
#pragma unroll
    for (int mi = 0; mi < MI; ++mi)
#pragma unroll
      for (int kk = 0; kk < 2; ++kk)
        a[mi][kk] = *(const s8v*)(smc + (P ? AO * 2 : 0) +
            (wrow + QR * (BM / 4) + mi * 16 + lr) * 128 + ((kk * 64 + lg * 16) ^ swz));
  };
  auto LDB = [&](int P, int QC, s8v bb[2][2]) {
#pragma unroll
    for (int ni = 0; ni < 2; ++ni)
#pragma unroll
      for (int kk = 0; kk < 2; ++kk)
        bb[ni][kk] = *(const s8v*)(smc + (P ? BO * 2 : BE * 2) +
            (wn * 64 + QC * 32 + ni * 16 + lr) * 128 + ((kk * 64 + lg * 16) ^ swz));
  };

  f4v acc[BM / 32][4];
#pragma unroll
  for (int i = 0; i < BM / 32; ++i)
#pragma unroll
    for (int j = 0; j < 4; ++j) acc[i][j] = {0.f, 0.f, 0.f, 0.f};

#define PHMF(QR, QC, B)                                                        \
  __builtin_amdgcn_s_setprio(1);                                               \
  _Pragma("unroll") for (int mi = 0; mi < MI; ++mi)                            \
    _Pragma("unroll") for (int ni = 0; ni < 2; ++ni)                           \
      _Pragma("unroll") for (int kk = 0; kk < 2; ++kk)                         \
        acc[(QR) * MI + mi][(QC) * 2 + ni] =                                   \
            MFMA(a[mi][kk], B[ni][kk], acc[(QR) * MI + mi][(QC) * 2 + ni]);    \
  __builtin_amdgcn_s_setprio(0);

  // prologue: even slot fully + odd B halves
  STB(0, 0, 0); STB(0, 1, 0);
  STA(0, 0, 0); STA(0, 1, 0);
  STB(1, 0, 1); STB(1, 1, 1);
  asm volatile("s_waitcnt vmcnt(4)" ::: "memory");
  bar();

  const int ITERS = K >> 7;
  for (int i = 0; i < ITERS; ++i) {
    const int kn = 2 * i + 2;
    const bool more = (i + 1 < ITERS);
    LDA(0, 0); LDB(0, 0, b0);
    STA(1, 0, 2 * i + 1);
    bar(); PHMF(0, 0, b0); bar();
    LDB(0, 1, b1);
    STA(1, 1, 2 * i + 1);
    bar(); PHMF(0, 1, b1); bar();
    LDA(0, 1);
    if (more) STB(0, 0, kn);
    bar(); PHMF(1, 1, b1); bar();
    if (more) STB(0, 1, kn);
    bar(); PHMF(1, 0, b0);
    asm volatile("s_waitcnt vmcnt(4)" ::: "memory");
    bar();
    LDA(1, 0); LDB(1, 0, b0);
    if (more) STA(0, 0, kn);
    bar(); PHMF(0, 0, b0); bar();
    LDB(1, 1, b1);
    if (more) STA(0, 1, kn);
    bar(); PHMF(0, 1, b1); bar();
    LDA(1, 1);
    if (more) STB(1, 0, 2 * i + 3);
    bar(); PHMF(1, 1, b1); bar();
    if (more) STB(1, 1, 2 * i + 3);
    bar(); PHMF(1, 0, b0);
    asm volatile("s_waitcnt vmcnt(4)" ::: "memory");
    bar();
  }
#undef PHMF

  bar();   // all LDS tile reads done; smem now reused as epilogue scratch

  if (MODE == 2) {
    const int mt = m0 >> 8;
    if (mt < 20) {
      // token-major output via per-wave LDS transpose (bf16)
      u16* dst; int fstride, fbase; const float* bias;
      if (mt < 16) { dst = Cq; fstride = 4096; fbase = m0;        bias = bA; }
      else         { dst = Ck; fstride = 1024; fbase = m0 - 4096; bias = bB; }
      u16* buf = smem + wv * 4352;   // [32 tok][136 feat]
#pragma unroll
      for (int c = 0; c < 2; ++c) {
#pragma unroll
        for (int fj2 = 0; fj2 < 2; ++fj2) {
          const int fj = 2 * c + fj2;
          const int tl = fj2 * 16 + lr;
#pragma unroll
          for (int fi = 0; fi < BM / 32; ++fi)
#pragma unroll
            for (int r = 0; r < 4; ++r) {
              const int fl = fi * 16 + lg * 4 + r;
              buf[tl * 136 + fl] = f2b(acc[fi][fj][r] + bias[fbase + wrow + fl]);
            }
        }
        asm volatile("s_waitcnt lgkmcnt(0)" ::: "memory");
        const int row = l >> 1, half = l & 1;
        const int tok = n0 + wn * 64 + c * 32 + row;
        const u16* src = buf + row * 136 + half * 64;
        u16* g = dst + (size_t)tok * fstride + fbase + wrow + half * 64;
#pragma unroll
        for (int i = 0; i < 8; ++i)
          *(s8v*)(g + i * 8) = *(const s8v*)(src + i * 8);
        asm volatile("s_waitcnt lgkmcnt(0)" ::: "memory");
      }
    } else {
      // vT: feature-major, direct write
#pragma unroll
      for (int fi = 0; fi < BM / 32; ++fi)
#pragma unroll
        for (int fj = 0; fj < 4; ++fj)
#pragma unroll
          for (int r = 0; r < 4; ++r) {
            const int feat = m0 - 5120 + wrow + fi * 16 + lg * 4 + r;
            const int tok = n0 + wn * 64 + fj * 16 + lr;
            Cv[(size_t)feat * 2048 + tok] = f2b(acc[fi][fj][r] + bC[feat]);
          }
    }
  } else {
    // fp32 out[tok][4096] via per-wave LDS transpose
    float* buf = (float*)smem + wv * 1088;   // [16 tok][68 feat]
#pragma unroll
    for (int c = 0; c < 4; ++c) {
#pragma unroll
      for (int fi = 0; fi < BM / 32; ++fi)
#pragma unroll
        for (int r = 0; r < 4; ++r) {
          const int fl = fi * 16 + lg * 4 + r;
          buf[lr * 68 + fl] = acc[fi][c][r] + bA[m0 + wrow + fl];
        }
      asm volatile("s_waitcnt lgkmcnt(0)" ::: "memory");
      const int row = l >> 2, q4 = l & 3;
      const int tok = n0 + wn * 64 + c * 16 + row;
      float* g = Cf + (size_t)tok * 4096 + m0 + wrow + q4 * 16;
      const float* src = buf + row * 68 + q4 * 16;
#pragma unroll
      for (int i = 0; i < 4; ++i)
        *(f4v*)(g + i * 4) = *(const f4v*)(src + i * 4);
      asm volatile("s_waitcnt lgkmcnt(0)" ::: "memory");
    }
  }
}

// ---------------- RoPE (in place on bf16 q,k) ----------------
__global__ void rope_kernel(u16* __restrict__ q, u16* __restrict__ k, const int* __restrict__ pos) {
  int i = blockIdx.x * 256 + threadIdx.x;
  const int NQ = 2048 * 32 * 64;
  const int NK = 2048 * 8 * 64;
  u16* buf;
  int m, d, stride, h;
  if (i < NQ) { buf = q; m = i >> 11; h = (i >> 6) & 31; d = i & 63; stride = 4096; }
  else {
    i -= NQ; if (i >= NK) return;
    buf = k; m = i >> 9; h = (i >> 6) & 7; d = i & 63; stride = 1024;
  }
  size_t base = (size_t)m * stride + h * 128 + d;
  float a = b2f(buf[base]), b = b2f(buf[base + 64]);
  float p = (float)pos[m];
  float ang = p * exp2f(-0.20762050593045952f * (float)d);
  float s, c;
  sincosf(ang, &s, &c);
  buf[base]      = f2b(a * c - b * s);
  buf[base + 64] = f2b(b * c + a * s);
}

// ---------------- flash attention ----------------
__global__ __launch_bounds__(512, 4) void attn_kernel(const u16* __restrict__ Q, const u16* __restrict__ Kb,
                                                      const u16* __restrict__ Vt, u16* __restrict__ Ao) {
  __shared__ __align__(16) u16 Ks[64 * 128];
  __shared__ __align__(16) u16 Vs[128 * 64];
  __shared__ __align__(16) u16 Ps[8 * 16 * 64];
  const int tid = threadIdx.x;
  const int l = tid & 63, wv = tid >> 6;
  const int lr = l & 15, lg = l >> 4;
  const int head = blockIdx.x >> 4, qt = blockIdx.x & 15;
  const int kh = head >> 2;
  const int qrow = qt * 128 + wv * 16 + lr;

  s8v qf[4];
#pragma unroll
  for (int s = 0; s < 4; ++s)
    qf[s] = *(const s8v*)&Q[(size_t)qrow * 4096 + head * 128 + s * 32 + lg * 8];

  f4v zero = {0.f, 0.f, 0.f, 0.f};
  f4v ao[8];
#pragma unroll
  for (int tt = 0; tt < 8; ++tt) ao[tt] = zero;
  float mrun = -1e30f, lrun = 0.f;

  const int ki0 = tid, ki1 = tid + 512;
  const int kr0 = ki0 >> 4, kc0 = (ki0 & 15) ^ (kr0 & 7);
  const int kr1 = ki1 >> 4, kc1 = (ki1 & 15) ^ (kr1 & 7);
  const int vr0 = ki0 >> 3, vc0 = (ki0 & 7) ^ (vr0 & 7);
  const int vr1 = ki1 >> 3, vc1 = (ki1 & 7) ^ (vr1 & 7);
  const u16* Kg = Kb + kh * 128;
  const u16* Vg = Vt + (size_t)(kh * 128) * 2048;
  const u16* kp0 = Kg + (size_t)kr0 * 1024 + kc0 * 8;
  const u16* kp1 = Kg + (size_t)kr1 * 1024 + kc1 * 8;
  const u16* vp0 = Vg + (size_t)vr0 * 2048 + vc0 * 8;
  const u16* vp1 = Vg + (size_t)vr1 * 2048 + vc1 * 8;

  char* KsB = (char*)Ks;
  char* VsB = (char*)Vs;
  char* PwB = (char*)Ps + wv * 2048;
  const int swz = 16 * (lr & 7);
  const float C2 = 0.12753102f;         // (1/sqrt(128)) * log2(e)

  for (int t = 0; t < 2048; t += 64) {
    __syncthreads();
    gll16(kp0 + (size_t)t * 1024, KsB + ki0 * 16);
    gll16(kp1 + (size_t)t * 1024, KsB + ki1 * 16);
    gll16(vp0 + t,                VsB + ki0 * 16);
    gll16(vp1 + t,                VsB + ki1 * 16);
    __syncthreads();

    f4v c[4];
#pragma unroll
    for (int j = 0; j < 4; ++j) c[j] = zero;
#pragma unroll
    for (int s = 0; s < 4; ++s) {
#pragma unroll
      for (int j = 0; j < 4; ++j) {
        s8v kf = *(const s8v*)(KsB + (16 * j + lr) * 256 + (((4 * s + lg) * 16) ^ swz));
        c[j] = MFMA(kf, qf[s], c[j]);
      }
    }

    float mx = fmaxf(fmaxf(c[0][0], c[0][1]), fmaxf(c[0][2], c[0][3]));
#pragma unroll
    for (int j = 1; j < 4; ++j)
      mx = fmaxf(mx, fmaxf(fmaxf(c[j][0], c[j][1]), fmaxf(c[j][2], c[j][3])));
    mx = fmaxf(mx, __shfl_xor(mx, 16));
    mx = fmaxf(mx, __shfl_xor(mx, 32));
    float m2x = mx * C2;

    if (!__all(m2x - mrun <= 8.f)) {
      float mnew = fmaxf(mrun, m2x);
      float alpha = __builtin_amdgcn_exp2f(mrun - mnew);
      float ar[4];
#pragma unroll
      for (int r = 0; r < 4; ++r) ar[r] = __shfl(alpha, 4 * lg + r);
#pragma unroll
      for (int tt = 0; tt < 8; ++tt)
#pragma unroll
        for (int r = 0; r < 4; ++r) ao[tt][r] *= ar[r];
      lrun *= alpha;
      mrun = mnew;
    }

    float rs = 0.f;
#pragma unroll
    for (int j = 0; j < 4; ++j) {
      float p0 = __builtin_amdgcn_exp2f(__builtin_fmaf(c[j][0], C2, -mrun));
      float p1 = __builtin_amdgcn_exp2f(__builtin_fmaf(c[j][1], C2, -mrun));
      float p2 = __builtin_amdgcn_exp2f(__builtin_fmaf(c[j][2], C2, -mrun));
      float p3 = __builtin_amdgcn_exp2f(__builtin_fmaf(c[j][3], C2, -mrun));
      rs += (p0 + p1) + (p2 + p3);
      uint32_t lo = (uint32_t)f2b(p0) | ((uint32_t)f2b(p1) << 16);
      uint32_t hi = (uint32_t)f2b(p2) | ((uint32_t)f2b(p3) << 16);
      u64 pak = (u64)lo | ((u64)hi << 32);
      *(u64*)(PwB + lr * 128 + ((32 * j + 8 * lg) ^ swz)) = pak;
    }
    rs += __shfl_xor(rs, 16);
    rs += __shfl_xor(rs, 32);
    lrun += rs;

#pragma unroll
    for (int h = 0; h < 2; ++h) {
      s8v pf = *(const s8v*)(PwB + lr * 128 + ((64 * h + 16 * lg) ^ swz));
#pragma unroll
      for (int tt = 0; tt < 8; ++tt) {
        s8v vf = *(const s8v*)(VsB + (16 * tt + lr) * 128 + (((4 * h + lg) * 16) ^ swz));
        ao[tt] = MFMA(pf, vf, ao[tt]);
      }
    }
  }

  float inv = 1.f / lrun;
  float ir[4];
#pragma unroll
  for (int r = 0; r < 4; ++r) ir[r] = __shfl(inv, 4 * lg + r);
#pragma unroll
  for (int tt = 0; tt < 8; ++tt)
#pragma unroll
    for (int r = 0; r < 4; ++r)
      Ao[(size_t)(qt * 128 + wv * 16 + 4 * lg + r) * 4096 + head * 128 + 16 * tt + lr] =
          f2b(ao[tt][r] * ir[r]);
}

extern "C" void kernel_launch(void* const* d_in, const int* in_sizes, int n_in,
                              void* d_out, int out_size, void* d_ws, size_t ws_size,
                              hipStream_t stream) {
  const float* x  = (const float*)d_in[0];
  const int*   pos = (const int*)d_in[1];
  const float* wq = (const float*)d_in[2];
  const float* bq = (const float*)d_in[3];
  const float* wk = (const float*)d_in[4];
  const float* bk = (const float*)d_in[5];
  const float* wv = (const float*)d_in[6];
  const float* bv = (const float*)d_in[7];
  const float* wo = (const float*)d_in[8];
  const float* bo = (const float*)d_in[9];
  float* out = (float*)d_out;

  char* ws = (char*)d_ws;
  u16* xb   = (u16*)(ws + 0);           // 16 MB  x bf16 [2048][4096]
  u16* wqkv = (u16*)(ws + 16777216);    // 48 MB  wq|wk|wv bf16 [6144][4096]
  u16* wob  = (u16*)(ws + 67108864);    // 32 MB  wo bf16 [4096][4096]
  u16* qb   = (u16*)(ws + 100663296);   // 16 MB  q bf16 [2048][4096]
  u16* kb   = (u16*)(ws + 117440512);   //  4 MB  k bf16 [2048][1024]
  u16* vT   = (u16*)(ws + 121634816);   //  4 MB  v^T bf16 [1024][2048]
  u16* ab   = (u16*)(ws + 125829120);   // 16 MB  attn out bf16 [2048][4096]

  auto cv = [&](const float* s, u16* d, size_t n) {
    int n8 = (int)(n / 8);
    cvt_kernel<<<(n8 + 255) / 256, 256, 0, stream>>>(s, d, n8);
  };
  cv(x,  xb,   (size_t)2048 * 4096);
  cv(wq, wqkv, (size_t)4096 * 4096);
  cv(wk, wqkv + (size_t)4096 * 4096, (size_t)1024 * 4096);
  cv(wv, wqkv + (size_t)5120 * 4096, (size_t)1024 * 4096);
  cv(wo, wob,  (size_t)4096 * 4096);

  // QKV: A = weights [6144][4096], B = x [2048][4096]
  gemm8p<256, 2><<<192, 512, 131072, stream>>>(wqkv, xb, bq, bk, bv,
                                               nullptr, qb, kb, vT, 4096);
  rope_kernel<<<(2048 * 32 * 64 + 2048 * 8 * 64) / 256, 256, 0, stream>>>(qb, kb, pos);
  attn_kernel<<<512, 512, 0, stream>>>(qb, kb, vT, ab);
  // O-proj: A = wo [4096][4096], B = ab [2048][4096], fp32 out
  gemm8p<128, 0><<<256, 512, 98304, stream>>>(wob, ab, bo, nullptr, nullptr,
                                              out, nullptr, nullptr, nullptr, 4096);
}

// Round 5
// 326.122 us; speedup vs baseline: 1.8741x; 1.0641x over previous
//
#include <hip/hip_runtime.h>
#include <stdint.h>

typedef unsigned short u16;
typedef unsigned long long u64;
typedef __attribute__((ext_vector_type(8))) short s8v;
typedef __attribute__((ext_vector_type(4))) float f4v;

#define MFMA(a, b, c) __builtin_amdgcn_mfma_f32_16x16x32_bf16((a), (b), (c), 0, 0, 0)

__device__ __forceinline__ u16 f2b(float f) {
  uint32_t x = __float_as_uint(f);
  x += 0x7fff + ((x >> 16) & 1);   // RNE
  return (u16)(x >> 16);
}
__device__ __forceinline__ float b2f(u16 u) {
  return __uint_as_float(((uint32_t)u) << 16);
}

// async global->LDS, 16B per lane. LDS dest must be wave-uniform base + lane*16.
__device__ __forceinline__ void gll16(const void* g, void* l) {
  __builtin_amdgcn_global_load_lds((const __attribute__((address_space(1))) uint32_t*)g,
                                   (__attribute__((address_space(3))) uint32_t*)l, 16, 0, 0);
}
__device__ __forceinline__ void bar() { __builtin_amdgcn_s_barrier(); }

// ---------------- fused fp32 -> bf16 convert (all 5 tensors, one dispatch) ----------------
__global__ void cvt_all(const float* __restrict__ x, const float* __restrict__ wq,
                        const float* __restrict__ wk, const float* __restrict__ wv,
                        const float* __restrict__ wo,
                        u16* __restrict__ xb, u16* __restrict__ wqkv, u16* __restrict__ wob) {
  int i = blockIdx.x * 256 + threadIdx.x;   // 8-elem chunk index
  const float* s; u16* d; size_t off;
  if      (i < 1048576) { s = x;  d = xb;   off = (size_t)i; }
  else if (i < 3145728) { s = wq; d = wqkv; off = (size_t)(i - 1048576); }
  else if (i < 3670016) { s = wk; d = wqkv + (size_t)16777216; off = (size_t)(i - 3145728); }
  else if (i < 4194304) { s = wv; d = wqkv + (size_t)20971520; off = (size_t)(i - 3670016); }
  else                  { s = wo; d = wob;  off = (size_t)(i - 4194304); }
  const float4* sp = (const float4*)(s + off * 8);
  float4 f0 = sp[0], f1 = sp[1];
  s8v o;
  o[0] = (short)f2b(f0.x); o[1] = (short)f2b(f0.y); o[2] = (short)f2b(f0.z); o[3] = (short)f2b(f0.w);
  o[4] = (short)f2b(f1.x); o[5] = (short)f2b(f1.y); o[6] = (short)f2b(f1.z); o[7] = (short)f2b(f1.w);
  *(s8v*)(d + off * 8) = o;
}

// ---------------- 8-phase GEMM, weights-as-A orientation ----------------
// A = weights [F][K] (M = features), B = activations [2048][K] (N = tokens).
// C[feat][tok] = sum_k A[feat][k]*B[tok][k] + bias[feat].
// BN=256 tokens, BK=64, 8 waves (2M x 4N), dbuf LDS, XOR swizzle, counted vmcnt.
// MODE 2 (BM=192): fused QKV, bias = concat bqkv[6144]; per-16-row-stripe region
//   routing (q/k token-major via LDS transpose, v feature-major direct).
// MODE 0 (BM=128): fp32 out[tok][4096] via LDS transpose.
template <int BM, int MODE>
__global__ __launch_bounds__(512, 2) void gemm8p(
    const u16* __restrict__ A, const u16* __restrict__ Bact,
    const float* __restrict__ bias,
    float* __restrict__ Cf, u16* __restrict__ Cq, u16* __restrict__ Ck, u16* __restrict__ Cv,
    int K) {
  extern __shared__ u16 smem[];
  constexpr int AO = BM * 64;          // A-odd elem offset
  constexpr int BE = 2 * BM * 64;      // B-even
  constexpr int BO = BE + 16384;       // B-odd
  constexpr int MI = BM / 64;          // A frags per quadrant
  constexpr int NH = BM / 64;          // A staging rounds per slot (64 rows each)

  const int tid = threadIdx.x;
  const int l = tid & 63, wv = tid >> 6;
  const int wm = wv >> 2, wn = wv & 3;
  const int lr = l & 15, lg = l >> 4;
  const int swz = 16 * (lr & 7);
  const int wrow = wm * (BM / 2);

  // XCD-aware swizzle, m-major logical order (per-XCD L2 reuse of A across token tiles)
  const int nwg = gridDim.x;
  int bid = blockIdx.x;
  bid = (bid & 7) * (nwg >> 3) + (bid >> 3);
  const int NB = 8;                    // 2048 tokens / 256
  const int m0 = (bid / NB) * BM, n0 = (bid % NB) * 256;

  const size_t K64 = (size_t)64 * K;

  const int sr = tid >> 3;
  const int sc = ((tid & 7) ^ (sr & 7)) * 8;
  const u16* gA = A + (size_t)(m0 + sr) * K + sc;
  const u16* gB = Bact + (size_t)(n0 + sr) * K + sc;

  auto STA = [&](int P, int h, int kt) {   // stage A rows [64h, 64h+64)
    gll16(gA + (size_t)(h * 64) * K + (size_t)kt * 64,
          smem + (P ? AO : 0) + h * 4096 + tid * 8);
  };
  auto STB = [&](int P, int h, int kt) {   // stage B rows [128h, 128h+128)
    const u16* g = gB + (size_t)(h * 128) * K + (size_t)kt * 64;
    u16* d = smem + (P ? BO : BE) + h * 8192 + tid * 8;
    gll16(g, d);
    gll16(g + K64, d + 4096);
  };

  const char* smc = (const char*)smem;
  s8v a[MI][2], b0[2][2], b1[2][2];
  auto LDA = [&](int P, int QR) {
#pragma unroll
    for (int mi = 0; mi < MI; ++mi)
#pragma unroll
      for (int kk = 0; kk < 2; ++kk)
        a[mi][kk] = *(const s8v*)(smc + (P ? AO * 2 : 0) +
            (wrow + QR * (BM / 4) + mi * 16 + lr) * 128 + ((kk * 64 + lg * 16) ^ swz));
  };
  auto LDB = [&](int P, int QC, s8v bb[2][2]) {
#pragma unroll
    for (int ni = 0; ni < 2; ++ni)
#pragma unroll
      for (int kk = 0; kk < 2; ++kk)
        bb[ni][kk] = *(const s8v*)(smc + (P ? BO * 2 : BE * 2) +
            (wn * 64 + QC * 32 + ni * 16 + lr) * 128 + ((kk * 64 + lg * 16) ^ swz));
  };

  f4v acc[BM / 32][4];
#pragma unroll
  for (int i = 0; i < BM / 32; ++i)
#pragma unroll
    for (int j = 0; j < 4; ++j) acc[i][j] = {0.f, 0.f, 0.f, 0.f};

#define PHMF(QR, QC, B)                                                        \
  __builtin_amdgcn_s_setprio(1);                                               \
  _Pragma("unroll") for (int mi = 0; mi < MI; ++mi)                            \
    _Pragma("unroll") for (int ni = 0; ni < 2; ++ni)                           \
      _Pragma("unroll") for (int kk = 0; kk < 2; ++kk)                         \
        acc[(QR) * MI + mi][(QC) * 2 + ni] =                                   \
            MFMA(a[mi][kk], B[ni][kk], acc[(QR) * MI + mi][(QC) * 2 + ni]);    \
  __builtin_amdgcn_s_setprio(0);

  // prologue: even slot fully + odd B halves
  STB(0, 0, 0); STB(0, 1, 0);
#pragma unroll
  for (int h = 0; h < NH; ++h) STA(0, h, 0);
  STB(1, 0, 1); STB(1, 1, 1);
  asm volatile("s_waitcnt vmcnt(4)" ::: "memory");
  bar();

  const int ITERS = K >> 7;
  for (int i = 0; i < ITERS; ++i) {
    const int kn = 2 * i + 2;
    const bool more = (i + 1 < ITERS);
    // phi1
    LDA(0, 0); LDB(0, 0, b0);
    STA(1, 0, 2 * i + 1);
    bar(); PHMF(0, 0, b0); bar();
    // phi2
    LDB(0, 1, b1);
    STA(1, 1, 2 * i + 1);
    bar(); PHMF(0, 1, b1); bar();
    // phi3
    LDA(0, 1);
    if constexpr (NH > 2) STA(1, 2, 2 * i + 1);
    if (more) STB(0, 0, kn);
    bar(); PHMF(1, 1, b1); bar();
    // phi4: counted wait (A-odd + prior B-odd must be done; next B-even may fly)
    if (more) STB(0, 1, kn);
    bar(); PHMF(1, 0, b0);
    if (more) asm volatile("s_waitcnt vmcnt(4)" ::: "memory");
    else      asm volatile("s_waitcnt vmcnt(0)" ::: "memory");
    bar();
    // phi5
    LDA(1, 0); LDB(1, 0, b0);
    if (more) STA(0, 0, kn);
    bar(); PHMF(0, 0, b0); bar();
    // phi6
    LDB(1, 1, b1);
    if (more) STA(0, 1, kn);
    bar(); PHMF(0, 1, b1); bar();
    // phi7
    LDA(1, 1);
    if (more) {
      if constexpr (NH > 2) STA(0, 2, kn);
      STB(1, 0, 2 * i + 3);
    }
    bar(); PHMF(1, 1, b1); bar();
    // phi8
    if (more) STB(1, 1, 2 * i + 3);
    bar(); PHMF(1, 0, b0);
    asm volatile("s_waitcnt vmcnt(4)" ::: "memory");
    bar();
  }
#undef PHMF

  bar();   // LDS now reusable as epilogue scratch

  if constexpr (MODE == 2) {
    // V stripes (feat >= 5120): feature-major direct write
#pragma unroll
    for (int fi = 0; fi < BM / 32; ++fi) {
      const int f0 = m0 + wrow + fi * 16;
      if (f0 >= 5120) {
#pragma unroll
        for (int fj = 0; fj < 4; ++fj)
#pragma unroll
          for (int r = 0; r < 4; ++r) {
            const int f = f0 + lg * 4 + r;
            const int tok = n0 + wn * 64 + fj * 16 + lr;
            Cv[(size_t)(f - 5120) * 2048 + tok] = f2b(acc[fi][fj][r] + bias[f]);
          }
      }
    }
    // Q/K stripes: token-major via per-wave LDS transpose
    if (m0 + wrow < 5120) {
      u16* buf = smem + wv * 3328;     // [32 tok][104 feats]
#pragma unroll
      for (int c = 0; c < 2; ++c) {
#pragma unroll
        for (int fj2 = 0; fj2 < 2; ++fj2) {
          const int fj = 2 * c + fj2;
          const int tl = fj2 * 16 + lr;
#pragma unroll
          for (int fi = 0; fi < BM / 32; ++fi) {
            const int f0 = m0 + wrow + fi * 16;
            if (f0 < 5120) {
#pragma unroll
              for (int r = 0; r < 4; ++r) {
                const int fl = fi * 16 + lg * 4 + r;
                buf[tl * 104 + fl] = f2b(acc[fi][fj][r] + bias[m0 + wrow + fl]);
              }
            }
          }
        }
        asm volatile("s_waitcnt lgkmcnt(0)" ::: "memory");
        const int row = l >> 1, half = l & 1;
        const int tok = n0 + wn * 64 + c * 32 + row;
#pragma unroll
        for (int i2 = 0; i2 < 6; ++i2) {
          const int flc = (2 * i2 + half) * 8;       // 16B-aligned chunk
          const int f = m0 + wrow + flc;
          if (f < 4096)
            *(s8v*)(Cq + (size_t)tok * 4096 + f) = *(const s8v*)(buf + row * 104 + flc);
          else if (f < 5120)
            *(s8v*)(Ck + (size_t)tok * 1024 + (f - 4096)) = *(const s8v*)(buf + row * 104 + flc);
        }
        asm volatile("s_waitcnt lgkmcnt(0)" ::: "memory");
      }
    }
  } else {
    // fp32 out[tok][4096] via per-wave LDS transpose
    float* buf = (float*)smem + wv * 1088;   // [16 tok][68 feat]
#pragma unroll
    for (int c = 0; c < 4; ++c) {
#pragma unroll
      for (int fi = 0; fi < BM / 32; ++fi)
#pragma unroll
        for (int r = 0; r < 4; ++r) {
          const int fl = fi * 16 + lg * 4 + r;
          buf[lr * 68 + fl] = acc[fi][c][r] + bias[m0 + wrow + fl];
        }
      asm volatile("s_waitcnt lgkmcnt(0)" ::: "memory");
      const int row = l >> 2, q4 = l & 3;
      const int tok = n0 + wn * 64 + c * 16 + row;
      float* g = Cf + (size_t)tok * 4096 + m0 + wrow + q4 * 16;
      const float* src = buf + row * 68 + q4 * 16;
#pragma unroll
      for (int i2 = 0; i2 < 4; ++i2)
        *(f4v*)(g + i2 * 4) = *(const f4v*)(src + i2 * 4);
      asm volatile("s_waitcnt lgkmcnt(0)" ::: "memory");
    }
  }
}

// ---------------- RoPE (in place on bf16 q,k) ----------------
__global__ void rope_kernel(u16* __restrict__ q, u16* __restrict__ k, const int* __restrict__ pos) {
  int i = blockIdx.x * 256 + threadIdx.x;
  const int NQ = 2048 * 32 * 64;
  const int NK = 2048 * 8 * 64;
  u16* buf;
  int m, d, stride, h;
  if (i < NQ) { buf = q; m = i >> 11; h = (i >> 6) & 31; d = i & 63; stride = 4096; }
  else {
    i -= NQ; if (i >= NK) return;
    buf = k; m = i >> 9; h = (i >> 6) & 7; d = i & 63; stride = 1024;
  }
  size_t base = (size_t)m * stride + h * 128 + d;
  float a = b2f(buf[base]), b = b2f(buf[base + 64]);
  float p = (float)pos[m];
  float ang = p * exp2f(-0.20762050593045952f * (float)d);
  float s, c;
  sincosf(ang, &s, &c);
  buf[base]      = f2b(a * c - b * s);
  buf[base + 64] = f2b(b * c + a * s);
}

// ---------------- flash attention ----------------
__global__ __launch_bounds__(512, 4) void attn_kernel(const u16* __restrict__ Q, const u16* __restrict__ Kb,
                                                      const u16* __restrict__ Vt, u16* __restrict__ Ao) {
  __shared__ __align__(16) u16 Ks[64 * 128];
  __shared__ __align__(16) u16 Vs[128 * 64];
  __shared__ __align__(16) u16 Ps[8 * 16 * 64];
  const int tid = threadIdx.x;
  const int l = tid & 63, wv = tid >> 6;
  const int lr = l & 15, lg = l >> 4;
  const int head = blockIdx.x >> 4, qt = blockIdx.x & 15;
  const int kh = head >> 2;
  const int qrow = qt * 128 + wv * 16 + lr;

  s8v qf[4];
#pragma unroll
  for (int s = 0; s < 4; ++s)
    qf[s] = *(const s8v*)&Q[(size_t)qrow * 4096 + head * 128 + s * 32 + lg * 8];

  f4v zero = {0.f, 0.f, 0.f, 0.f};
  f4v ao[8];
#pragma unroll
  for (int tt = 0; tt < 8; ++tt) ao[tt] = zero;
  float mrun = -1e30f, lrun = 0.f;

  const int ki0 = tid, ki1 = tid + 512;
  const int kr0 = ki0 >> 4, kc0 = (ki0 & 15) ^ (kr0 & 7);
  const int kr1 = ki1 >> 4, kc1 = (ki1 & 15) ^ (kr1 & 7);
  const int vr0 = ki0 >> 3, vc0 = (ki0 & 7) ^ (vr0 & 7);
  const int vr1 = ki1 >> 3, vc1 = (ki1 & 7) ^ (vr1 & 7);
  const u16* Kg = Kb + kh * 128;
  const u16* Vg = Vt + (size_t)(kh * 128) * 2048;
  const u16* kp0 = Kg + (size_t)kr0 * 1024 + kc0 * 8;
  const u16* kp1 = Kg + (size_t)kr1 * 1024 + kc1 * 8;
  const u16* vp0 = Vg + (size_t)vr0 * 2048 + vc0 * 8;
  const u16* vp1 = Vg + (size_t)vr1 * 2048 + vc1 * 8;

  char* KsB = (char*)Ks;
  char* VsB = (char*)Vs;
  char* PwB = (char*)Ps + wv * 2048;
  const int swz = 16 * (lr & 7);
  const float C2 = 0.12753102f;         // (1/sqrt(128)) * log2(e)

  for (int t = 0; t < 2048; t += 64) {
    __syncthreads();
    gll16(kp0 + (size_t)t * 1024, KsB + ki0 * 16);
    gll16(kp1 + (size_t)t * 1024, KsB + ki1 * 16);
    gll16(vp0 + t,                VsB + ki0 * 16);
    gll16(vp1 + t,                VsB + ki1 * 16);
    __syncthreads();

    f4v c[4];
#pragma unroll
    for (int j = 0; j < 4; ++j) c[j] = zero;
#pragma unroll
    for (int s = 0; s < 4; ++s) {
#pragma unroll
      for (int j = 0; j < 4; ++j) {
        s8v kf = *(const s8v*)(KsB + (16 * j + lr) * 256 + (((4 * s + lg) * 16) ^ swz));
        c[j] = MFMA(kf, qf[s], c[j]);
      }
    }

    float mx = fmaxf(fmaxf(c[0][0], c[0][1]), fmaxf(c[0][2], c[0][3]));
#pragma unroll
    for (int j = 1; j < 4; ++j)
      mx = fmaxf(mx, fmaxf(fmaxf(c[j][0], c[j][1]), fmaxf(c[j][2], c[j][3])));
    mx = fmaxf(mx, __shfl_xor(mx, 16));
    mx = fmaxf(mx, __shfl_xor(mx, 32));
    float m2x = mx * C2;

    if (!__all(m2x - mrun <= 8.f)) {
      float mnew = fmaxf(mrun, m2x);
      float alpha = __builtin_amdgcn_exp2f(mrun - mnew);
      float ar[4];
#pragma unroll
      for (int r = 0; r < 4; ++r) ar[r] = __shfl(alpha, 4 * lg + r);
#pragma unroll
      for (int tt = 0; tt < 8; ++tt)
#pragma unroll
        for (int r = 0; r < 4; ++r) ao[tt][r] *= ar[r];
      lrun *= alpha;
      mrun = mnew;
    }

    float rs = 0.f;
#pragma unroll
    for (int j = 0; j < 4; ++j) {
      float p0 = __builtin_amdgcn_exp2f(__builtin_fmaf(c[j][0], C2, -mrun));
      float p1 = __builtin_amdgcn_exp2f(__builtin_fmaf(c[j][1], C2, -mrun));
      float p2 = __builtin_amdgcn_exp2f(__builtin_fmaf(c[j][2], C2, -mrun));
      float p3 = __builtin_amdgcn_exp2f(__builtin_fmaf(c[j][3], C2, -mrun));
      rs += (p0 + p1) + (p2 + p3);
      uint32_t lo = (uint32_t)f2b(p0) | ((uint32_t)f2b(p1) << 16);
      uint32_t hi = (uint32_t)f2b(p2) | ((uint32_t)f2b(p3) << 16);
      u64 pak = (u64)lo | ((u64)hi << 32);
      *(u64*)(PwB + lr * 128 + ((32 * j + 8 * lg) ^ swz)) = pak;
    }
    rs += __shfl_xor(rs, 16);
    rs += __shfl_xor(rs, 32);
    lrun += rs;

#pragma unroll
    for (int h = 0; h < 2; ++h) {
      s8v pf = *(const s8v*)(PwB + lr * 128 + ((64 * h + 16 * lg) ^ swz));
#pragma unroll
      for (int tt = 0; tt < 8; ++tt) {
        s8v vf = *(const s8v*)(VsB + (16 * tt + lr) * 128 + (((4 * h + lg) * 16) ^ swz));
        ao[tt] = MFMA(pf, vf, ao[tt]);
      }
    }
  }

  float inv = 1.f / lrun;
  float ir[4];
#pragma unroll
  for (int r = 0; r < 4; ++r) ir[r] = __shfl(inv, 4 * lg + r);
#pragma unroll
  for (int tt = 0; tt < 8; ++tt)
#pragma unroll
    for (int r = 0; r < 4; ++r)
      Ao[(size_t)(qt * 128 + wv * 16 + 4 * lg + r) * 4096 + head * 128 + 16 * tt + lr] =
          f2b(ao[tt][r] * ir[r]);
}

extern "C" void kernel_launch(void* const* d_in, const int* in_sizes, int n_in,
                              void* d_out, int out_size, void* d_ws, size_t ws_size,
                              hipStream_t stream) {
  const float* x  = (const float*)d_in[0];
  const int*   pos = (const int*)d_in[1];
  const float* wq = (const float*)d_in[2];
  const float* bq = (const float*)d_in[3];
  const float* wk = (const float*)d_in[4];
  const float* bk = (const float*)d_in[5];
  const float* wv = (const float*)d_in[6];
  const float* bv = (const float*)d_in[7];
  const float* wo = (const float*)d_in[8];
  const float* bo = (const float*)d_in[9];
  float* out = (float*)d_out;

  char* ws = (char*)d_ws;
  u16* xb   = (u16*)(ws + 0);           // 16 MB  x bf16 [2048][4096]
  u16* wqkv = (u16*)(ws + 16777216);    // 48 MB  wq|wk|wv bf16 [6144][4096]
  u16* wob  = (u16*)(ws + 67108864);    // 32 MB  wo bf16 [4096][4096]
  u16* qb   = (u16*)(ws + 100663296);   // 16 MB  q bf16 [2048][4096]
  u16* kb   = (u16*)(ws + 117440512);   //  4 MB  k bf16 [2048][1024]
  u16* vT   = (u16*)(ws + 121634816);   //  4 MB  v^T bf16 [1024][2048]
  u16* ab   = (u16*)(ws + 125829120);   // 16 MB  attn out bf16 [2048][4096]
  float* bqkv = (float*)(ws + 142606336); // 24 KB concat bias [6144] fp32

  // concat biases (device-to-device, async)
  hipMemcpyAsync(bqkv,        bq, 4096 * sizeof(float), hipMemcpyDeviceToDevice, stream);
  hipMemcpyAsync(bqkv + 4096, bk, 1024 * sizeof(float), hipMemcpyDeviceToDevice, stream);
  hipMemcpyAsync(bqkv + 5120, bv, 1024 * sizeof(float), hipMemcpyDeviceToDevice, stream);

  cvt_all<<<24576, 256, 0, stream>>>(x, wq, wk, wv, wo, xb, wqkv, wob);

  // QKV: A = wqkv [6144][4096], B = x [2048][4096]; BM=192 -> 32x8 = 256 blocks
  gemm8p<192, 2><<<256, 512, 114688, stream>>>(wqkv, xb, bqkv,
                                               nullptr, qb, kb, vT, 4096);
  rope_kernel<<<(2048 * 32 * 64 + 2048 * 8 * 64) / 256, 256, 0, stream>>>(qb, kb, pos);
  attn_kernel<<<512, 512, 0, stream>>>(qb, kb, vT, ab);
  // O-proj: A = wo [4096][4096], B = ab [2048][4096], fp32 out; 32x8 = 256 blocks
  gemm8p<128, 0><<<256, 512, 98304, stream>>>(wob, ab, bo,
                                              out, nullptr, nullptr, nullptr, 4096);
}

// Round 9
// 326.107 us; speedup vs baseline: 1.8742x; 1.0000x over previous
//
#include <hip/hip_runtime.h>
#include <stdint.h>

typedef unsigned short u16;
typedef unsigned long long u64;
typedef __attribute__((ext_vector_type(8))) short s8v;
typedef __attribute__((ext_vector_type(4))) float f4v;

#define MFMA(a, b, c) __builtin_amdgcn_mfma_f32_16x16x32_bf16((a), (b), (c), 0, 0, 0)

__device__ __forceinline__ u16 f2b(float f) {
  uint32_t x = __float_as_uint(f);
  x += 0x7fff + ((x >> 16) & 1);   // RNE
  return (u16)(x >> 16);
}
__device__ __forceinline__ float b2f(u16 u) {
  return __uint_as_float(((uint32_t)u) << 16);
}

// async global->LDS, 16B per lane. LDS dest must be wave-uniform base + lane*16.
__device__ __forceinline__ void gll16(const void* g, void* l) {
  __builtin_amdgcn_global_load_lds((const __attribute__((address_space(1))) uint32_t*)g,
                                   (__attribute__((address_space(3))) uint32_t*)l, 16, 0, 0);
}
__device__ __forceinline__ void bar() { __builtin_amdgcn_s_barrier(); }

// ---------------- fused fp32 -> bf16 convert (all 5 tensors, one dispatch) ----------------
__global__ void cvt_all(const float* __restrict__ x, const float* __restrict__ wq,
                        const float* __restrict__ wk, const float* __restrict__ wv,
                        const float* __restrict__ wo,
                        u16* __restrict__ xb, u16* __restrict__ wqkv, u16* __restrict__ wob) {
  int i = blockIdx.x * 256 + threadIdx.x;   // 8-elem chunk index
  const float* s; u16* d; size_t off;
  if      (i < 1048576) { s = x;  d = xb;   off = (size_t)i; }
  else if (i < 3145728) { s = wq; d = wqkv; off = (size_t)(i - 1048576); }
  else if (i < 3670016) { s = wk; d = wqkv + (size_t)16777216; off = (size_t)(i - 3145728); }
  else if (i < 4194304) { s = wv; d = wqkv + (size_t)20971520; off = (size_t)(i - 3670016); }
  else                  { s = wo; d = wob;  off = (size_t)(i - 4194304); }
  const float4* sp = (const float4*)(s + off * 8);
  float4 f0 = sp[0], f1 = sp[1];
  s8v o;
  o[0] = (short)f2b(f0.x); o[1] = (short)f2b(f0.y); o[2] = (short)f2b(f0.z); o[3] = (short)f2b(f0.w);
  o[4] = (short)f2b(f1.x); o[5] = (short)f2b(f1.y); o[6] = (short)f2b(f1.z); o[7] = (short)f2b(f1.w);
  *(s8v*)(d + off * 8) = o;
}

// ---------------- 8-phase GEMM, weights-as-A orientation (round-5 green) ----------------
// A = weights [F][K] (M = features), B = activations [2048][K] (N = tokens).
// C[feat][tok] = sum_k A[feat][k]*B[tok][k] + bias[feat].
// BN=256 tokens, BK=64, 8 waves (2M x 4N), dbuf LDS, XOR swizzle, counted vmcnt.
// MODE 2 (BM=192): fused QKV, bias = concat bqkv[6144]; per-16-row-stripe region
//   routing (q/k token-major via LDS transpose, v feature-major direct).
// MODE 0 (BM=128): fp32 out[tok][4096] via LDS transpose.
template <int BM, int MODE>
__global__ __launch_bounds__(512, 2) void gemm8p(
    const u16* __restrict__ A, const u16* __restrict__ Bact,
    const float* __restrict__ bias,
    float* __restrict__ Cf, u16* __restrict__ Cq, u16* __restrict__ Ck, u16* __restrict__ Cv,
    int K) {
  extern __shared__ u16 smem[];
  constexpr int AO = BM * 64;          // A-odd elem offset
  constexpr int BE = 2 * BM * 64;      // B-even
  constexpr int BO = BE + 16384;       // B-odd
  constexpr int MI = BM / 64;          // A frags per quadrant
  constexpr int NH = BM / 64;          // A staging rounds per slot (64 rows each)

  const int tid = threadIdx.x;
  const int l = tid & 63, wv = tid >> 6;
  const int wm = wv >> 2, wn = wv & 3;
  const int lr = l & 15, lg = l >> 4;
  const int swz = 16 * (lr & 7);
  const int wrow = wm * (BM / 2);

  // XCD-aware swizzle, m-major logical order (per-XCD L2 reuse of A across token tiles)
  const int nwg = gridDim.x;
  int bid = blockIdx.x;
  bid = (bid & 7) * (nwg >> 3) + (bid >> 3);
  const int NB = 8;                    // 2048 tokens / 256
  const int m0 = (bid / NB) * BM, n0 = (bid % NB) * 256;

  const size_t K64 = (size_t)64 * K;

  const int sr = tid >> 3;
  const int sc = ((tid & 7) ^ (sr & 7)) * 8;
  const u16* gA = A + (size_t)(m0 + sr) * K + sc;
  const u16* gB = Bact + (size_t)(n0 + sr) * K + sc;

  auto STA = [&](int P, int h, int kt) {   // stage A rows [64h, 64h+64)
    gll16(gA + (size_t)(h * 64) * K + (size_t)kt * 64,
          smem + (P ? AO : 0) + h * 4096 + tid * 8);
  };
  auto STB = [&](int P, int h, int kt) {   // stage B rows [128h, 128h+128)
    const u16* g = gB + (size_t)(h * 128) * K + (size_t)kt * 64;
    u16* d = smem + (P ? BO : BE) + h * 8192 + tid * 8;
    gll16(g, d);
    gll16(g + K64, d + 4096);
  };

  const char* smc = (const char*)smem;
  s8v a[MI][2], b0[2][2], b1[2][2];
  auto LDA = [&](int P, int QR) {
#pragma unroll
    for (int mi = 0; mi < MI; ++mi)
#pragma unroll
      for (int kk = 0; kk < 2; ++kk)
        a[mi][kk] = *(const s8v*)(smc + (P ? AO * 2 : 0) +
            (wrow + QR * (BM / 4) + mi * 16 + lr) * 128 + ((kk * 64 + lg * 16) ^ swz));
  };
  auto LDB = [&](int P, int QC, s8v bb[2][2]) {
#pragma unroll
    for (int ni = 0; ni < 2; ++ni)
#pragma unroll
      for (int kk = 0; kk < 2; ++kk)
        bb[ni][kk] = *(const s8v*)(smc + (P ? BO * 2 : BE * 2) +
            (wn * 64 + QC * 32 + ni * 16 + lr) * 128 + ((kk * 64 + lg * 16) ^ swz));
  };

  f4v acc[BM / 32][4];
#pragma unroll
  for (int i = 0; i < BM / 32; ++i)
#pragma unroll
    for (int j = 0; j < 4; ++j) acc[i][j] = {0.f, 0.f, 0.f, 0.f};

#define PHMF(QR, QC, B)                                                        \
  __builtin_amdgcn_s_setprio(1);                                               \
  _Pragma("unroll") for (int mi = 0; mi < MI; ++mi)                            \
    _Pragma("unroll") for (int ni = 0; ni < 2; ++ni)                           \
      _Pragma("unroll") for (int kk = 0; kk < 2; ++kk)                         \
        acc[(QR) * MI + mi][(QC) * 2 + ni] =                                   \
            MFMA(a[mi][kk], B[ni][kk], acc[(QR) * MI + mi][(QC) * 2 + ni]);    \
  __builtin_amdgcn_s_setprio(0);

  // prologue: even slot fully + odd B halves; leftover = 4 odd-B loads
  STB(0, 0, 0); STB(0, 1, 0);
#pragma unroll
  for (int h = 0; h < NH; ++h) STA(0, h, 0);
  STB(1, 0, 1); STB(1, 1, 1);
  asm volatile("s_waitcnt vmcnt(4)" ::: "memory");
  bar();

  const int ITERS = K >> 7;
  for (int i = 0; i < ITERS; ++i) {
    const int kn = 2 * i + 2;
    const bool more = (i + 1 < ITERS);
    // phi1
    LDA(0, 0); LDB(0, 0, b0);
    STA(1, 0, 2 * i + 1);
    bar(); PHMF(0, 0, b0); bar();
    // phi2
    LDB(0, 1, b1);
    STA(1, 1, 2 * i + 1);
    bar(); PHMF(0, 1, b1); bar();
    // phi3
    LDA(0, 1);
    if constexpr (NH > 2) STA(1, 2, 2 * i + 1);
    if (more) STB(0, 0, kn);
    bar(); PHMF(1, 1, b1); bar();
    // phi4: counted wait (A-odd + prior B-odd done; next B-even may fly)
    if (more) STB(0, 1, kn);
    bar(); PHMF(1, 0, b0);
    if (more) asm volatile("s_waitcnt vmcnt(4)" ::: "memory");
    else      asm volatile("s_waitcnt vmcnt(0)" ::: "memory");
    bar();
    // phi5
    LDA(1, 0); LDB(1, 0, b0);
    if (more) STA(0, 0, kn);
    bar(); PHMF(0, 0, b0); bar();
    // phi6
    LDB(1, 1, b1);
    if (more) STA(0, 1, kn);
    bar(); PHMF(0, 1, b1); bar();
    // phi7
    LDA(1, 1);
    if (more) {
      if constexpr (NH > 2) STA(0, 2, kn);
      STB(1, 0, 2 * i + 3);
    }
    bar(); PHMF(1, 1, b1); bar();
    // phi8
    if (more) STB(1, 1, 2 * i + 3);
    bar(); PHMF(1, 0, b0);
    asm volatile("s_waitcnt vmcnt(4)" ::: "memory");
    bar();
  }
#undef PHMF

  bar();   // LDS now reusable as epilogue scratch

  if constexpr (MODE == 2) {
    // V stripes (feat >= 5120): feature-major direct write
#pragma unroll
    for (int fi = 0; fi < BM / 32; ++fi) {
      const int f0 = m0 + wrow + fi * 16;
      if (f0 >= 5120) {
#pragma unroll
        for (int fj = 0; fj < 4; ++fj)
#pragma unroll
          for (int r = 0; r < 4; ++r) {
            const int f = f0 + lg * 4 + r;
            const int tok = n0 + wn * 64 + fj * 16 + lr;
            Cv[(size_t)(f - 5120) * 2048 + tok] = f2b(acc[fi][fj][r] + bias[f]);
          }
      }
    }
    // Q/K stripes: token-major via per-wave LDS transpose
    if (m0 + wrow < 5120) {
      u16* buf = smem + wv * 3328;     // [32 tok][104 feats]
#pragma unroll
      for (int c = 0; c < 2; ++c) {
#pragma unroll
        for (int fj2 = 0; fj2 < 2; ++fj2) {
          const int fj = 2 * c + fj2;
          const int tl = fj2 * 16 + lr;
#pragma unroll
          for (int fi = 0; fi < BM / 32; ++fi) {
            const int f0 = m0 + wrow + fi * 16;
            if (f0 < 5120) {
#pragma unroll
              for (int r = 0; r < 4; ++r) {
                const int fl = fi * 16 + lg * 4 + r;
                buf[tl * 104 + fl] = f2b(acc[fi][fj][r] + bias[m0 + wrow + fl]);
              }
            }
          }
        }
        asm volatile("s_waitcnt lgkmcnt(0)" ::: "memory");
        const int row = l >> 1, half = l & 1;
        const int tok = n0 + wn * 64 + c * 32 + row;
#pragma unroll
        for (int i2 = 0; i2 < 6; ++i2) {
          const int flc = (2 * i2 + half) * 8;       // 16B-aligned chunk
          const int f = m0 + wrow + flc;
          if (f < 4096)
            *(s8v*)(Cq + (size_t)tok * 4096 + f) = *(const s8v*)(buf + row * 104 + flc);
          else if (f < 5120)
            *(s8v*)(Ck + (size_t)tok * 1024 + (f - 4096)) = *(const s8v*)(buf + row * 104 + flc);
        }
        asm volatile("s_waitcnt lgkmcnt(0)" ::: "memory");
      }
    }
  } else {
    // fp32 out[tok][4096] via per-wave LDS transpose
    float* buf = (float*)smem + wv * 1088;   // [16 tok][68 feat]
#pragma unroll
    for (int c = 0; c < 4; ++c) {
#pragma unroll
      for (int fi = 0; fi < BM / 32; ++fi)
#pragma unroll
        for (int r = 0; r < 4; ++r) {
          const int fl = fi * 16 + lg * 4 + r;
          buf[lr * 68 + fl] = acc[fi][c][r] + bias[m0 + wrow + fl];
        }
      asm volatile("s_waitcnt lgkmcnt(0)" ::: "memory");
      const int row = l >> 2, q4 = l & 3;
      const int tok = n0 + wn * 64 + c * 16 + row;
      float* g = Cf + (size_t)tok * 4096 + m0 + wrow + q4 * 16;
      const float* src = buf + row * 68 + q4 * 16;
#pragma unroll
      for (int i2 = 0; i2 < 4; ++i2)
        *(f4v*)(g + i2 * 4) = *(const f4v*)(src + i2 * 4);
      asm volatile("s_waitcnt lgkmcnt(0)" ::: "memory");
    }
  }
}

// ---------------- RoPE (in place on bf16 q,k) ----------------
__global__ void rope_kernel(u16* __restrict__ q, u16* __restrict__ k, const int* __restrict__ pos) {
  int i = blockIdx.x * 256 + threadIdx.x;
  const int NQ = 2048 * 32 * 64;
  const int NK = 2048 * 8 * 64;
  u16* buf;
  int m, d, stride, h;
  if (i < NQ) { buf = q; m = i >> 11; h = (i >> 6) & 31; d = i & 63; stride = 4096; }
  else {
    i -= NQ; if (i >= NK) return;
    buf = k; m = i >> 9; h = (i >> 6) & 7; d = i & 63; stride = 1024;
  }
  size_t base = (size_t)m * stride + h * 128 + d;
  float a = b2f(buf[base]), b = b2f(buf[base + 64]);
  float p = (float)pos[m];
  float ang = p * exp2f(-0.20762050593045952f * (float)d);
  float s, c;
  sincosf(ang, &s, &c);
  buf[base]      = f2b(a * c - b * s);
  buf[base + 64] = f2b(b * c + a * s);
}

// ---------------- flash attention (round-5 green structure) ----------------
__global__ __launch_bounds__(512, 4) void attn_kernel(const u16* __restrict__ Q, const u16* __restrict__ Kb,
                                                      const u16* __restrict__ Vt, u16* __restrict__ Ao) {
  __shared__ __align__(16) u16 Ks[64 * 128];
  __shared__ __align__(16) u16 Vs[128 * 64];
  __shared__ __align__(16) u16 Ps[8][16 * 64];
  const int tid = threadIdx.x;
  const int l = tid & 63, wv = tid >> 6;
  const int lr = l & 15, lg = l >> 4;
  const int head = blockIdx.x >> 4, qt = blockIdx.x & 15;
  const int kh = head >> 2;
  const int qrow = qt * 128 + wv * 16 + lr;

  s8v qf[4];
#pragma unroll
  for (int s = 0; s < 4; ++s)
    qf[s] = *(const s8v*)&Q[(size_t)qrow * 4096 + head * 128 + s * 32 + lg * 8];

  f4v zero = {0.f, 0.f, 0.f, 0.f};
  f4v ao[8];
#pragma unroll
  for (int tt = 0; tt < 8; ++tt) ao[tt] = zero;
  float mrun = -1e30f, lrun = 0.f;

  const int ki0 = tid, ki1 = tid + 512;
  const int kr0 = ki0 >> 4, kc0 = (ki0 & 15) ^ (kr0 & 7);
  const int kr1 = ki1 >> 4, kc1 = (ki1 & 15) ^ (kr1 & 7);
  const int vr0 = ki0 >> 3, vc0 = (ki0 & 7) ^ (vr0 & 7);
  const int vr1 = ki1 >> 3, vc1 = (ki1 & 7) ^ (vr1 & 7);
  const u16* Kg = Kb + kh * 128;
  const u16* Vg = Vt + (size_t)(kh * 128) * 2048;
  const u16* kp0 = Kg + (size_t)kr0 * 1024 + kc0 * 8;
  const u16* kp1 = Kg + (size_t)kr1 * 1024 + kc1 * 8;
  const u16* vp0 = Vg + (size_t)vr0 * 2048 + vc0 * 8;
  const u16* vp1 = Vg + (size_t)vr1 * 2048 + vc1 * 8;

  char* KsB = (char*)Ks;
  char* VsB = (char*)Vs;
  char* PwB = (char*)Ps[wv];
  const int swz = 16 * (lr & 7);
  const float C2 = 0.12753102f;         // (1/sqrt(128)) * log2(e)

  for (int t = 0; t < 2048; t += 64) {
    __syncthreads();
    gll16(kp0 + (size_t)t * 1024, KsB + ki0 * 16);
    gll16(kp1 + (size_t)t * 1024, KsB + ki1 * 16);
    gll16(vp0 + t,                VsB + ki0 * 16);
    gll16(vp1 + t,                VsB + ki1 * 16);
    __syncthreads();

    f4v c[4];
#pragma unroll
    for (int j = 0; j < 4; ++j) c[j] = zero;
#pragma unroll
    for (int s = 0; s < 4; ++s) {
#pragma unroll
      for (int j = 0; j < 4; ++j) {
        s8v kf = *(const s8v*)(KsB + (16 * j + lr) * 256 + (((4 * s + lg) * 16) ^ swz));
        c[j] = MFMA(kf, qf[s], c[j]);
      }
    }

    float mx = fmaxf(fmaxf(c[0][0], c[0][1]), fmaxf(c[0][2], c[0][3]));
#pragma unroll
    for (int j = 1; j < 4; ++j)
      mx = fmaxf(mx, fmaxf(fmaxf(c[j][0], c[j][1]), fmaxf(c[j][2], c[j][3])));
    mx = fmaxf(mx, __shfl_xor(mx, 16));
    mx = fmaxf(mx, __shfl_xor(mx, 32));
    float m2x = mx * C2;

    if (!__all(m2x - mrun <= 8.f)) {      // defer-max
      float mnew = fmaxf(mrun, m2x);
      float alpha = __builtin_amdgcn_exp2f(mrun - mnew);
      float ar[4];
#pragma unroll
      for (int r = 0; r < 4; ++r) ar[r] = __shfl(alpha, 4 * lg + r);
#pragma unroll
      for (int tt = 0; tt < 8; ++tt)
#pragma unroll
        for (int r = 0; r < 4; ++r) ao[tt][r] *= ar[r];
      lrun *= alpha;
      mrun = mnew;
    }

    float rs = 0.f;
#pragma unroll
    for (int j = 0; j < 4; ++j) {
      float p0 = __builtin_amdgcn_exp2f(__builtin_fmaf(c[j][0], C2, -mrun));
      float p1 = __builtin_amdgcn_exp2f(__builtin_fmaf(c[j][1], C2, -mrun));
      float p2 = __builtin_amdgcn_exp2f(__builtin_fmaf(c[j][2], C2, -mrun));
      float p3 = __builtin_amdgcn_exp2f(__builtin_fmaf(c[j][3], C2, -mrun));
      rs += (p0 + p1) + (p2 + p3);
      uint32_t lo = (uint32_t)f2b(p0) | ((uint32_t)f2b(p1) << 16);
      uint32_t hi = (uint32_t)f2b(p2) | ((uint32_t)f2b(p3) << 16);
      u64 pak = (u64)lo | ((u64)hi << 32);
      *(u64*)(PwB + lr * 128 + ((32 * j + 8 * lg) ^ swz)) = pak;
    }
    rs += __shfl_xor(rs, 16);
    rs += __shfl_xor(rs, 32);
    lrun += rs;

#pragma unroll
    for (int h = 0; h < 2; ++h) {
      s8v pf = *(const s8v*)(PwB + lr * 128 + ((64 * h + 16 * lg) ^ swz));
#pragma unroll
      for (int tt = 0; tt < 8; ++tt) {
        s8v vf = *(const s8v*)(VsB + (16 * tt + lr) * 128 + (((4 * h + lg) * 16) ^ swz));
        ao[tt] = MFMA(pf, vf, ao[tt]);
      }
    }
  }

  float inv = 1.f / lrun;
  float ir[4];
#pragma unroll
  for (int r = 0; r < 4; ++r) ir[r] = __shfl(inv, 4 * lg + r);
#pragma unroll
  for (int tt = 0; tt < 8; ++tt)
#pragma unroll
    for (int r = 0; r < 4; ++r)
      Ao[(size_t)(qt * 128 + wv * 16 + 4 * lg + r) * 4096 + head * 128 + 16 * tt + lr] =
          f2b(ao[tt][r] * ir[r]);
}

extern "C" void kernel_launch(void* const* d_in, const int* in_sizes, int n_in,
                              void* d_out, int out_size, void* d_ws, size_t ws_size,
                              hipStream_t stream) {
  const float* x  = (const float*)d_in[0];
  const int*   pos = (const int*)d_in[1];
  const float* wq = (const float*)d_in[2];
  const float* bq = (const float*)d_in[3];
  const float* wk = (const float*)d_in[4];
  const float* bk = (const float*)d_in[5];
  const float* wv = (const float*)d_in[6];
  const float* bv = (const float*)d_in[7];
  const float* wo = (const float*)d_in[8];
  const float* bo = (const float*)d_in[9];
  float* out = (float*)d_out;

  char* ws = (char*)d_ws;
  u16* xb   = (u16*)(ws + 0);           // 16 MB  x bf16 [2048][4096]
  u16* wqkv = (u16*)(ws + 16777216);    // 48 MB  wq|wk|wv bf16 [6144][4096]
  u16* wob  = (u16*)(ws + 67108864);    // 32 MB  wo bf16 [4096][4096]
  u16* qb   = (u16*)(ws + 100663296);   // 16 MB  q bf16 [2048][4096]
  u16* kb   = (u16*)(ws + 117440512);   //  4 MB  k bf16 [2048][1024]
  u16* vT   = (u16*)(ws + 121634816);   //  4 MB  v^T bf16 [1024][2048]
  u16* ab   = (u16*)(ws + 125829120);   // 16 MB  attn out bf16 [2048][4096]
  float* bqkv = (float*)(ws + 142606336); // 24 KB concat bias [6144] fp32

  hipMemcpyAsync(bqkv,        bq, 4096 * sizeof(float), hipMemcpyDeviceToDevice, stream);
  hipMemcpyAsync(bqkv + 4096, bk, 1024 * sizeof(float), hipMemcpyDeviceToDevice, stream);
  hipMemcpyAsync(bqkv + 5120, bv, 1024 * sizeof(float), hipMemcpyDeviceToDevice, stream);

  cvt_all<<<24576, 256, 0, stream>>>(x, wq, wk, wv, wo, xb, wqkv, wob);

  // QKV: A = wqkv [6144][4096], B = x [2048][4096]; BM=192 -> 32x8 = 256 blocks
  gemm8p<192, 2><<<256, 512, 114688, stream>>>(wqkv, xb, bqkv,
                                               nullptr, qb, kb, vT, 4096);
  rope_kernel<<<(2048 * 32 * 64 + 2048 * 8 * 64) / 256, 256, 0, stream>>>(qb, kb, pos);
  attn_kernel<<<512, 512, 0, stream>>>(qb, kb, vT, ab);
  // O-proj: A = wo [4096][4096], B = ab [2048][4096], fp32 out; 32x8 = 256 blocks
  gemm8p<128, 0><<<256, 512, 98304, stream>>>(wob, ab, bo,
                                              out, nullptr, nullptr, nullptr, 4096);
}